// Round 5
// baseline (591.460 us; speedup 1.0000x reference)
//
#include <hip/hip_runtime.h>
#include <hip/hip_bf16.h>
#include <cmath>

// ---------------------------------------------------------------------------
// GCN: out = tanh(relu(relu(relu(relu(P(P(P(P(xW1+..)..) .. ))Wf1+bf1)Wf2+bf2
// P = D^-1/2 (A+I) D^-1/2 via CSR (dst-sorted) gather-sum, no float atomics.
// Associativity: aggregate at the *narrower* width of each layer.
// edge_index arrives as int32 (harness converts int64 inputs).
// R3: gemm<64,128,RT=8> spilled (VGPR=256, 895MB scratch). R4: M-split fixed it.
// R4 found fill_kernel at 105us: 155MB scatter-write traffic (12x ideal) from
// two 4B scatters/edge thrashing lines across 8 XCD L2s.
// R5: CSR stores src ONLY (one 4B scatter/edge); w=dinv[s]*dinv[d] recomputed
// in agg (dinv is 400KB -> L2-resident gather). dinv fused into scan1.
// ---------------------------------------------------------------------------

__global__ void zero_kernel(int* p, int n) {
    int i = blockIdx.x * 256 + threadIdx.x;
    if (i < n) p[i] = 0;
}

__global__ void deg_kernel(const int* __restrict__ dst, int* __restrict__ cnt, int E) {
    int e = blockIdx.x * 256 + threadIdx.x;
    if (e < E) atomicAdd(&cnt[dst[e]], 1);
}

// --- scan1 (+ fused dinv): block-local exclusive scan of cnt ---------------
__global__ void scan1_kernel(const int* __restrict__ cnt, int* __restrict__ row_ptr,
                             int* __restrict__ blk, float* __restrict__ dinv, int N) {
    __shared__ int s[256];
    int t = threadIdx.x;
    int idx = blockIdx.x * 256 + t;
    int v = (idx < N) ? cnt[idx] : 0;
    if (idx < N) dinv[idx] = rsqrtf((float)v + 1.0f);
    s[t] = v; __syncthreads();
    for (int off = 1; off < 256; off <<= 1) {
        int x = (t >= off) ? s[t - off] : 0;
        __syncthreads();
        s[t] += x;
        __syncthreads();
    }
    if (idx < N) row_ptr[idx] = s[t] - v;
    if (t == 255) blk[blockIdx.x] = s[255];
}

__global__ void scan2_kernel(int* __restrict__ blk, int NB) {
    __shared__ int s[512];
    int t = threadIdx.x;
    int v = (t < NB) ? blk[t] : 0;
    s[t] = v; __syncthreads();
    for (int off = 1; off < 512; off <<= 1) {
        int x = (t >= off) ? s[t - off] : 0;
        __syncthreads();
        s[t] += x;
        __syncthreads();
    }
    if (t < NB) blk[t] = s[t] - v;
}

__global__ void scan3_kernel(int* __restrict__ row_ptr, const int* __restrict__ blk,
                             int* __restrict__ cursor, int N, int E) {
    int idx = blockIdx.x * 256 + threadIdx.x;
    if (idx < N) {
        int v = row_ptr[idx] + blk[blockIdx.x];
        row_ptr[idx] = v;
        cursor[idx] = v;
    }
    if (idx == 0) row_ptr[N] = E;
}

// --- fill: ONE 4B scatter per edge (src only) ------------------------------
__global__ void fill_kernel(const int* __restrict__ src, const int* __restrict__ dst,
                            int* __restrict__ cursor, int* __restrict__ csr_src, int E) {
    int e = blockIdx.x * 256 + threadIdx.x;
    if (e >= E) return;
    int d = dst[e];
    int pos = atomicAdd(&cursor[d], 1);
    csr_src[pos] = src[e];
}

// --- aggregation: out[i,:] = sum_e dinv[s]*dinv[i]*z[s,:] + dinv[i]^2*z[i,:]
// one wave per node; F/4 lanes per edge-slot read the row as float4;
// butterfly float4 shuffle over slot bits. w recomputed from L2-resident dinv.
template<int F, bool L1MODE>
__global__ __launch_bounds__(256) void agg_kernel(
        const float* __restrict__ z, const int* __restrict__ row_ptr,
        const int* __restrict__ csr_src, const float* __restrict__ dinv,
        const float* __restrict__ bias, float* __restrict__ out, int N) {
    constexpr int G = F / 4;       // lanes per row
    constexpr int S = 64 / G;      // edge slots per wave
    const int t = threadIdx.x;
    const int wave = t >> 6;
    const int lane = t & 63;
    const int slot = lane / G;
    const int f4 = lane % G;       // float4 index within row
    const int i = blockIdx.x * 4 + wave;
    if (i >= N) return;            // wave-uniform exit
    const int start = row_ptr[i];
    const int end = row_ptr[i + 1];
    const float di = dinv[i];      // broadcast (one address per wave)
    float4 acc = {0.f, 0.f, 0.f, 0.f};
    for (int e = start + slot; e < end; e += S) {
        int s = csr_src[e];
        float w = dinv[s] * di;
        float4 zv = *(const float4*)&z[(size_t)s * F + f4 * 4];
        acc.x += w * zv.x; acc.y += w * zv.y; acc.z += w * zv.z; acc.w += w * zv.w;
    }
#pragma unroll
    for (int off = G; off < 64; off <<= 1) {
        acc.x += __shfl_xor(acc.x, off);
        acc.y += __shfl_xor(acc.y, off);
        acc.z += __shfl_xor(acc.z, off);
        acc.w += __shfl_xor(acc.w, off);
    }
    if (slot == 0) {
        float d2 = di * di;
        float4 zs = *(const float4*)&z[(size_t)i * F + f4 * 4];
        float4 r;
        r.x = acc.x + d2 * zs.x; r.y = acc.y + d2 * zs.y;
        r.z = acc.z + d2 * zs.z; r.w = acc.w + d2 * zs.w;
        if (L1MODE) {
            float4 bv = *(const float4*)&bias[f4 * 4];
            r.x = fmaxf(r.x + bv.x, 0.f); r.y = fmaxf(r.y + bv.y, 0.f);
            r.z = fmaxf(r.z + bv.z, 0.f); r.w = fmaxf(r.w + bv.w, 0.f);
        }
        *(float4*)&out[(size_t)i * F + f4 * 4] = r;
    }
}

// --- register-tiled GEMM: 64-row x MB-col tile per 256-thread block ---------
// grid.x = ceil(N/64) * (M/MB). thread: RT rows x 4 cols => RT float4 accs.
template<int K, int M, int MB, int RT, bool BIAS_RELU>
__global__ __launch_bounds__(256) void gemm_kernel(
        const float* __restrict__ A, const float* __restrict__ W,
        const float* __restrict__ bias, float* __restrict__ out, int N) {
    constexpr int CG = MB / 4;
    constexpr int TM = (256 / CG) * RT;
    constexpr int KP = K + 4;            // 2-way bank alias on As reads (free)
    constexpr int MSPLIT = M / MB;
    static_assert(TM == 64, "tile rows");
    __shared__ float As[TM * KP];
    __shared__ float Ws[K * MB];
    __shared__ float bs[MB];
    const int t = threadIdx.x;
    const int base = (blockIdx.x / MSPLIT) * TM;
    const int colb = (blockIdx.x % MSPLIT) * MB;
    const int rows_valid = min(TM, N - base);
    constexpr int KD4 = K / 4;
    for (int idx = t; idx < TM * KD4; idx += 256) {
        int row = idx / KD4, kc = idx % KD4;
        if (row < rows_valid)
            *(float4*)&As[row * KP + kc * 4] = *(const float4*)&A[(size_t)(base + row) * K + kc * 4];
    }
    constexpr int MD4 = MB / 4;
    for (int idx = t; idx < K * MD4; idx += 256) {
        int k = idx / MD4, c4 = idx % MD4;
        *(float4*)&Ws[k * MB + c4 * 4] = *(const float4*)&W[(size_t)k * M + colb + c4 * 4];
    }
    if (BIAS_RELU && t < MB) bs[t] = bias[colb + t];
    __syncthreads();

    const int tc = t % CG;
    const int r0 = (t / CG) * RT;
    const int c0 = tc * 4;
    float4 acc[RT];
#pragma unroll
    for (int r = 0; r < RT; r++) acc[r] = {0.f, 0.f, 0.f, 0.f};

#pragma unroll 4
    for (int k = 0; k < K; k += 4) {
        float4 w0 = *(const float4*)&Ws[(k + 0) * MB + c0];
        float4 w1 = *(const float4*)&Ws[(k + 1) * MB + c0];
        float4 w2 = *(const float4*)&Ws[(k + 2) * MB + c0];
        float4 w3 = *(const float4*)&Ws[(k + 3) * MB + c0];
#pragma unroll
        for (int r = 0; r < RT; r++) {
            float4 av = *(const float4*)&As[(r0 + r) * KP + k];
            acc[r].x += av.x * w0.x + av.y * w1.x + av.z * w2.x + av.w * w3.x;
            acc[r].y += av.x * w0.y + av.y * w1.y + av.z * w2.y + av.w * w3.y;
            acc[r].z += av.x * w0.z + av.y * w1.z + av.z * w2.z + av.w * w3.z;
            acc[r].w += av.x * w0.w + av.y * w1.w + av.z * w2.w + av.w * w3.w;
        }
    }
#pragma unroll
    for (int r = 0; r < RT; r++) {
        int row = base + r0 + r;
        if (row < N) {
            float4 v = acc[r];
            if (BIAS_RELU) {
                float4 bv = *(const float4*)&bs[c0];
                v.x = fmaxf(v.x + bv.x, 0.f); v.y = fmaxf(v.y + bv.y, 0.f);
                v.z = fmaxf(v.z + bv.z, 0.f); v.w = fmaxf(v.w + bv.w, 0.f);
            }
            *(float4*)&out[(size_t)row * M + colb + c0] = v;
        }
    }
}

// --- final FC: K=32, M=10, tanh --------------------------------------------
__global__ __launch_bounds__(256) void fc2_tanh_kernel(
        const float* __restrict__ A, const float* __restrict__ W,
        const float* __restrict__ bias, float* __restrict__ out, int N) {
    __shared__ float wt[10][36];
    __shared__ float bs[10];
    int t = threadIdx.x;
    for (int idx = t; idx < 320; idx += 256) { int k = idx / 10, m = idx % 10; wt[m][k] = W[idx]; }
    if (t < 10) bs[t] = bias[t];
    __syncthreads();
    int row = blockIdx.x * 256 + t;
    if (row >= N) return;
    float a[32];
    const float4* ap = (const float4*)(A + (size_t)row * 32);
#pragma unroll
    for (int j = 0; j < 8; j++) {
        float4 v = ap[j];
        a[4 * j] = v.x; a[4 * j + 1] = v.y; a[4 * j + 2] = v.z; a[4 * j + 3] = v.w;
    }
#pragma unroll
    for (int m = 0; m < 10; m++) {
        float acc = bs[m];
#pragma unroll
        for (int k = 0; k < 32; k++) acc += a[k] * wt[m][k];
        out[(size_t)row * 10 + m] = tanhf(acc);
    }
}

extern "C" void kernel_launch(void* const* d_in, const int* in_sizes, int n_in,
                              void* d_out, int out_size, void* d_ws, size_t ws_size,
                              hipStream_t stream) {
    const float* x   = (const float*)d_in[0];
    const int*   ei  = (const int*)d_in[1];     // int32 on device
    const float* W1  = (const float*)d_in[2];
    const float* b1  = (const float*)d_in[3];
    const float* W2  = (const float*)d_in[4];
    const float* b2  = (const float*)d_in[5];
    const float* W3  = (const float*)d_in[6];
    const float* b3  = (const float*)d_in[7];
    const float* W4  = (const float*)d_in[8];
    const float* b4  = (const float*)d_in[9];
    const float* Wf1 = (const float*)d_in[10];
    const float* bf1 = (const float*)d_in[11];
    const float* Wf2 = (const float*)d_in[12];
    const float* bf2 = (const float*)d_in[13];

    const int N = in_sizes[0] / 128;   // 100000
    const int E = in_sizes[1] / 2;     // 1600000
    const int* e_src = ei;
    const int* e_dst = ei + E;

    char* p = (char*)d_ws;
    auto carve = [&](size_t bytes) -> void* {
        void* r = (void*)p;
        p += (bytes + 255) & ~(size_t)255;
        return r;
    };
    int*   cnt     = (int*)carve((size_t)N * 4);          // reused as cursor
    float* dinv    = (float*)carve((size_t)N * 4);
    int*   row_ptr = (int*)carve((size_t)(N + 1) * 4);
    int*   blk     = (int*)carve(512 * 4);
    int*   csr_src = (int*)carve((size_t)E * 4);
    float* bufA    = (float*)carve((size_t)N * 64 * 4);
    float* bufB    = (float*)carve((size_t)N * 128 * 4);

    const int NB  = (N + 255) / 256;   // 391
    const int EB  = (E + 255) / 256;
    const int AGB = (N + 3) / 4;
    const int GB  = (N + 63) / 64;     // 1563 row-blocks

    // --- graph preprocessing: degree, dinv, CSR ---
    zero_kernel<<<NB, 256, 0, stream>>>(cnt, N);
    deg_kernel<<<EB, 256, 0, stream>>>(e_dst, cnt, E);
    scan1_kernel<<<NB, 256, 0, stream>>>(cnt, row_ptr, blk, dinv, N);
    scan2_kernel<<<1, 512, 0, stream>>>(blk, NB);
    scan3_kernel<<<NB, 256, 0, stream>>>(row_ptr, blk, cnt, N, E);
    fill_kernel<<<EB, 256, 0, stream>>>(e_src, e_dst, cnt, csr_src, E);

    // --- L1 (128->16): GEMM first (narrow side), then aggregate+bias+relu ---
    gemm_kernel<128, 16, 16, 1, false><<<GB, 256, 0, stream>>>(x, W1, nullptr, bufA, N);
    agg_kernel<16, true><<<AGB, 256, 0, stream>>>(bufA, row_ptr, csr_src, dinv, b1, bufB, N);

    // --- L2 (16->32): aggregate first, then GEMM+bias+relu ---
    agg_kernel<16, false><<<AGB, 256, 0, stream>>>(bufB, row_ptr, csr_src, dinv, nullptr, bufA, N);
    gemm_kernel<16, 32, 32, 2, true><<<GB, 256, 0, stream>>>(bufA, W2, b2, bufB, N);

    // --- L3 (32->64) ---
    agg_kernel<32, false><<<AGB, 256, 0, stream>>>(bufB, row_ptr, csr_src, dinv, nullptr, bufA, N);
    gemm_kernel<32, 64, 64, 4, true><<<GB, 256, 0, stream>>>(bufA, W3, b3, bufB, N);

    // --- L4 (64->128): aggregate at width 64, then M-split GEMM ---
    agg_kernel<64, false><<<AGB, 256, 0, stream>>>(bufB, row_ptr, csr_src, dinv, nullptr, bufA, N);
    gemm_kernel<64, 128, 64, 4, true><<<GB * 2, 256, 0, stream>>>(bufA, W4, b4, bufB, N);

    // --- FC head ---
    gemm_kernel<128, 32, 32, 2, true><<<GB, 256, 0, stream>>>(bufB, Wf1, bf1, bufA, N);
    fc2_tanh_kernel<<<NB, 256, 0, stream>>>(bufA, Wf2, bf2, (float*)d_out, N);
}

// Round 6
// 504.787 us; speedup vs baseline: 1.1717x; 1.1717x over previous
//
#include <hip/hip_runtime.h>
#include <hip/hip_bf16.h>
#include <cmath>

// ---------------------------------------------------------------------------
// GCN: out = tanh(relu(relu(relu(relu(P(P(P(P(xW1+..)..) .. ))Wf1+bf1)Wf2+bf2
// P = D^-1/2 (A+I) D^-1/2 via CSR (dst-sorted) gather-sum, no float atomics.
// Associativity: aggregate at the *narrower* width of each layer.
// edge_index arrives as int32 (harness converts int64 inputs).
// R3: gemm<64,128,RT=8> spilled -> R4 M-split fixed.
// R4/R5: direct CSR fill = 105-131us; WRITE_SIZE ~= E x 64B: every 4B scatter
// writes back a whole line (6.4MB target > 4MiB XCD L2, random pos).
// R6: two-phase bucketed build. Phase A: bucket by dst>>8 (391 buckets),
// per-block LDS hist + one atomic per (block,bucket) -> contiguous runs,
// write frontier = 391 lines (L2-resident). Phase B: one block per bucket
// sorts 256 nodes locally in LDS, emits row_ptr + csr_src (region-local
// writes). Replaces scan1/2/3 + cursor. agg/gemm unchanged.
// ---------------------------------------------------------------------------

#define NBUCK 391              // ceil(100000/256)
#define PREB  391              // ceil(E/4096) edge-phase blocks (16 edges/thread)

__global__ void zero_kernel(int* p, int n) {
    int i = blockIdx.x * 256 + threadIdx.x;
    if (i < n) p[i] = 0;
}

// degree + bucket histogram (16 edges/thread, LDS-aggregated bucket counts)
__global__ __launch_bounds__(256) void degbucket_kernel(
        const int* __restrict__ dst, int* __restrict__ cnt,
        int* __restrict__ bucket_cnt, int E) {
    __shared__ int bh[NBUCK];
    const int t = threadIdx.x;
    for (int i = t; i < NBUCK; i += 256) bh[i] = 0;
    __syncthreads();
    const int base = blockIdx.x * 4096;
#pragma unroll
    for (int j = 0; j < 16; j++) {
        int e = base + j * 256 + t;
        if (e < E) {
            int d = dst[e];
            atomicAdd(&cnt[d], 1);
            atomicAdd(&bh[d >> 8], 1);
        }
    }
    __syncthreads();
    for (int i = t; i < NBUCK; i += 256)
        if (bh[i]) atomicAdd(&bucket_cnt[i], bh[i]);
}

__global__ void dinv_kernel(const int* __restrict__ cnt, float* __restrict__ dinv, int N) {
    int i = blockIdx.x * 256 + threadIdx.x;
    if (i < N) dinv[i] = rsqrtf((float)cnt[i] + 1.0f);
}

// exclusive scan of bucket_cnt[NBUCK] -> bucket_start (ro) + bucket_cursor (rw)
__global__ void bucket_scan_kernel(const int* __restrict__ bucket_cnt,
                                   int* __restrict__ bucket_start,
                                   int* __restrict__ bucket_cursor, int E) {
    __shared__ int s[512];
    int t = threadIdx.x;
    int v = (t < NBUCK) ? bucket_cnt[t] : 0;
    s[t] = v; __syncthreads();
    for (int off = 1; off < 512; off <<= 1) {
        int x = (t >= off) ? s[t - off] : 0;
        __syncthreads();
        s[t] += x;
        __syncthreads();
    }
    if (t < NBUCK) {
        int excl = s[t] - v;
        bucket_start[t] = excl;
        bucket_cursor[t] = excl;
    }
    if (t == 0) bucket_start[NBUCK] = E;
}

// Phase A: scatter packed edges into bucket-grouped csr_tmp.
// payload = (dst&255)<<17 | src  (src < 2^17). runs per (block,bucket) are
// contiguous -> write frontier 391 lines, L2-resident.
__global__ __launch_bounds__(256) void place_kernel(
        const int* __restrict__ src, const int* __restrict__ dst,
        int* __restrict__ bucket_cursor, int* __restrict__ csr_tmp, int E) {
    __shared__ int hist[NBUCK];
    const int t = threadIdx.x;
    for (int i = t; i < NBUCK; i += 256) hist[i] = 0;
    __syncthreads();
    const int base = blockIdx.x * 4096;
    int pay[16], rb[16];
#pragma unroll
    for (int j = 0; j < 16; j++) {
        int e = base + j * 256 + t;
        if (e < E) {
            int d = dst[e];
            int b = d >> 8;
            int r = atomicAdd(&hist[b], 1);       // r < 4096
            pay[j] = ((d & 255) << 17) | src[e];
            rb[j] = (r << 9) | b;                 // b < 512
        } else rb[j] = -1;
    }
    __syncthreads();
    for (int i = t; i < NBUCK; i += 256) {
        int h = hist[i];
        hist[i] = h ? atomicAdd(&bucket_cursor[i], h) : 0;
    }
    __syncthreads();
#pragma unroll
    for (int j = 0; j < 16; j++) {
        if (rb[j] >= 0) {
            int b = rb[j] & 511;
            int r = rb[j] >> 9;
            csr_tmp[hist[b] + r] = pay[j];
        }
    }
}

// Phase B: one block per bucket -> per-node CSR (row_ptr + csr_src).
// All scatters confined to this bucket's ~16KB region.
__global__ __launch_bounds__(256) void bsort_kernel(
        const int* __restrict__ bucket_start, const int* __restrict__ csr_tmp,
        int* __restrict__ row_ptr, int* __restrict__ csr_src, int N, int E) {
    __shared__ int c[256], s[256], cur[256];
    const int b = blockIdx.x;
    const int t = threadIdx.x;
    const int start = bucket_start[b];
    const int end = bucket_start[b + 1];
    c[t] = 0;
    __syncthreads();
    for (int e = start + t; e < end; e += 256)
        atomicAdd(&c[csr_tmp[e] >> 17], 1);
    __syncthreads();
    int v = c[t];
    s[t] = v; __syncthreads();
    for (int off = 1; off < 256; off <<= 1) {
        int x = (t >= off) ? s[t - off] : 0;
        __syncthreads();
        s[t] += x;
        __syncthreads();
    }
    int excl = s[t] - v;
    int node = (b << 8) + t;
    if (node < N) row_ptr[node] = start + excl;
    cur[t] = start + excl;
    if (b == NBUCK - 1 && t == 0) row_ptr[N] = E;
    __syncthreads();
    for (int e = start + t; e < end; e += 256) {
        int p = csr_tmp[e];
        int pos = atomicAdd(&cur[p >> 17], 1);
        csr_src[pos] = p & 0x1FFFF;
    }
}

// --- aggregation: out[i,:] = sum_e dinv[s]*dinv[i]*z[s,:] + dinv[i]^2*z[i,:]
template<int F, bool L1MODE>
__global__ __launch_bounds__(256) void agg_kernel(
        const float* __restrict__ z, const int* __restrict__ row_ptr,
        const int* __restrict__ csr_src, const float* __restrict__ dinv,
        const float* __restrict__ bias, float* __restrict__ out, int N) {
    constexpr int G = F / 4;       // lanes per row
    constexpr int S = 64 / G;      // edge slots per wave
    const int t = threadIdx.x;
    const int wave = t >> 6;
    const int lane = t & 63;
    const int slot = lane / G;
    const int f4 = lane % G;
    const int i = blockIdx.x * 4 + wave;
    if (i >= N) return;            // wave-uniform exit
    const int start = row_ptr[i];
    const int end = row_ptr[i + 1];
    const float di = dinv[i];
    float4 acc = {0.f, 0.f, 0.f, 0.f};
    for (int e = start + slot; e < end; e += S) {
        int s = csr_src[e];
        float w = dinv[s] * di;
        float4 zv = *(const float4*)&z[(size_t)s * F + f4 * 4];
        acc.x += w * zv.x; acc.y += w * zv.y; acc.z += w * zv.z; acc.w += w * zv.w;
    }
#pragma unroll
    for (int off = G; off < 64; off <<= 1) {
        acc.x += __shfl_xor(acc.x, off);
        acc.y += __shfl_xor(acc.y, off);
        acc.z += __shfl_xor(acc.z, off);
        acc.w += __shfl_xor(acc.w, off);
    }
    if (slot == 0) {
        float d2 = di * di;
        float4 zs = *(const float4*)&z[(size_t)i * F + f4 * 4];
        float4 r;
        r.x = acc.x + d2 * zs.x; r.y = acc.y + d2 * zs.y;
        r.z = acc.z + d2 * zs.z; r.w = acc.w + d2 * zs.w;
        if (L1MODE) {
            float4 bv = *(const float4*)&bias[f4 * 4];
            r.x = fmaxf(r.x + bv.x, 0.f); r.y = fmaxf(r.y + bv.y, 0.f);
            r.z = fmaxf(r.z + bv.z, 0.f); r.w = fmaxf(r.w + bv.w, 0.f);
        }
        *(float4*)&out[(size_t)i * F + f4 * 4] = r;
    }
}

// --- register-tiled GEMM: 64-row x MB-col tile per 256-thread block ---------
template<int K, int M, int MB, int RT, bool BIAS_RELU>
__global__ __launch_bounds__(256) void gemm_kernel(
        const float* __restrict__ A, const float* __restrict__ W,
        const float* __restrict__ bias, float* __restrict__ out, int N) {
    constexpr int CG = MB / 4;
    constexpr int TM = (256 / CG) * RT;
    constexpr int KP = K + 4;            // 2-way bank alias on As reads (free)
    constexpr int MSPLIT = M / MB;
    static_assert(TM == 64, "tile rows");
    __shared__ float As[TM * KP];
    __shared__ float Ws[K * MB];
    __shared__ float bs[MB];
    const int t = threadIdx.x;
    const int base = (blockIdx.x / MSPLIT) * TM;
    const int colb = (blockIdx.x % MSPLIT) * MB;
    const int rows_valid = min(TM, N - base);
    constexpr int KD4 = K / 4;
    for (int idx = t; idx < TM * KD4; idx += 256) {
        int row = idx / KD4, kc = idx % KD4;
        if (row < rows_valid)
            *(float4*)&As[row * KP + kc * 4] = *(const float4*)&A[(size_t)(base + row) * K + kc * 4];
    }
    constexpr int MD4 = MB / 4;
    for (int idx = t; idx < K * MD4; idx += 256) {
        int k = idx / MD4, c4 = idx % MD4;
        *(float4*)&Ws[k * MB + c4 * 4] = *(const float4*)&W[(size_t)k * M + colb + c4 * 4];
    }
    if (BIAS_RELU && t < MB) bs[t] = bias[colb + t];
    __syncthreads();

    const int tc = t % CG;
    const int r0 = (t / CG) * RT;
    const int c0 = tc * 4;
    float4 acc[RT];
#pragma unroll
    for (int r = 0; r < RT; r++) acc[r] = {0.f, 0.f, 0.f, 0.f};

#pragma unroll 4
    for (int k = 0; k < K; k += 4) {
        float4 w0 = *(const float4*)&Ws[(k + 0) * MB + c0];
        float4 w1 = *(const float4*)&Ws[(k + 1) * MB + c0];
        float4 w2 = *(const float4*)&Ws[(k + 2) * MB + c0];
        float4 w3 = *(const float4*)&Ws[(k + 3) * MB + c0];
#pragma unroll
        for (int r = 0; r < RT; r++) {
            float4 av = *(const float4*)&As[(r0 + r) * KP + k];
            acc[r].x += av.x * w0.x + av.y * w1.x + av.z * w2.x + av.w * w3.x;
            acc[r].y += av.x * w0.y + av.y * w1.y + av.z * w2.y + av.w * w3.y;
            acc[r].z += av.x * w0.z + av.y * w1.z + av.z * w2.z + av.w * w3.z;
            acc[r].w += av.x * w0.w + av.y * w1.w + av.z * w2.w + av.w * w3.w;
        }
    }
#pragma unroll
    for (int r = 0; r < RT; r++) {
        int row = base + r0 + r;
        if (row < N) {
            float4 v = acc[r];
            if (BIAS_RELU) {
                float4 bv = *(const float4*)&bs[c0];
                v.x = fmaxf(v.x + bv.x, 0.f); v.y = fmaxf(v.y + bv.y, 0.f);
                v.z = fmaxf(v.z + bv.z, 0.f); v.w = fmaxf(v.w + bv.w, 0.f);
            }
            *(float4*)&out[(size_t)row * M + colb + c0] = v;
        }
    }
}

// --- final FC: K=32, M=10, tanh --------------------------------------------
__global__ __launch_bounds__(256) void fc2_tanh_kernel(
        const float* __restrict__ A, const float* __restrict__ W,
        const float* __restrict__ bias, float* __restrict__ out, int N) {
    __shared__ float wt[10][36];
    __shared__ float bs[10];
    int t = threadIdx.x;
    for (int idx = t; idx < 320; idx += 256) { int k = idx / 10, m = idx % 10; wt[m][k] = W[idx]; }
    if (t < 10) bs[t] = bias[t];
    __syncthreads();
    int row = blockIdx.x * 256 + t;
    if (row >= N) return;
    float a[32];
    const float4* ap = (const float4*)(A + (size_t)row * 32);
#pragma unroll
    for (int j = 0; j < 8; j++) {
        float4 v = ap[j];
        a[4 * j] = v.x; a[4 * j + 1] = v.y; a[4 * j + 2] = v.z; a[4 * j + 3] = v.w;
    }
#pragma unroll
    for (int m = 0; m < 10; m++) {
        float acc = bs[m];
#pragma unroll
        for (int k = 0; k < 32; k++) acc += a[k] * wt[m][k];
        out[(size_t)row * 10 + m] = tanhf(acc);
    }
}

extern "C" void kernel_launch(void* const* d_in, const int* in_sizes, int n_in,
                              void* d_out, int out_size, void* d_ws, size_t ws_size,
                              hipStream_t stream) {
    const float* x   = (const float*)d_in[0];
    const int*   ei  = (const int*)d_in[1];     // int32 on device
    const float* W1  = (const float*)d_in[2];
    const float* b1  = (const float*)d_in[3];
    const float* W2  = (const float*)d_in[4];
    const float* b2  = (const float*)d_in[5];
    const float* W3  = (const float*)d_in[6];
    const float* b3  = (const float*)d_in[7];
    const float* W4  = (const float*)d_in[8];
    const float* b4  = (const float*)d_in[9];
    const float* Wf1 = (const float*)d_in[10];
    const float* bf1 = (const float*)d_in[11];
    const float* Wf2 = (const float*)d_in[12];
    const float* bf2 = (const float*)d_in[13];

    const int N = in_sizes[0] / 128;   // 100000
    const int E = in_sizes[1] / 2;     // 1600000
    const int* e_src = ei;
    const int* e_dst = ei + E;

    char* p = (char*)d_ws;
    auto carve = [&](size_t bytes) -> void* {
        void* r = (void*)p;
        p += (bytes + 255) & ~(size_t)255;
        return r;
    };
    int*   cnt        = (int*)carve((size_t)N * 4);
    int*   bucket_cnt = (int*)carve(512 * 4);
    int*   bucket_sta = (int*)carve(512 * 4);
    int*   bucket_cur = (int*)carve(512 * 4);
    float* dinv       = (float*)carve((size_t)N * 4);
    int*   row_ptr    = (int*)carve((size_t)(N + 1) * 4);
    int*   csr_tmp    = (int*)carve((size_t)E * 4);
    int*   csr_src    = (int*)carve((size_t)E * 4);
    float* bufA       = (float*)carve((size_t)N * 64 * 4);
    float* bufB       = (float*)carve((size_t)N * 128 * 4);

    const int NB  = (N + 255) / 256;   // 391
    const int AGB = (N + 3) / 4;
    const int GB  = (N + 63) / 64;     // 1563 row-blocks
    // zero cnt + bucket_cnt in one launch (contiguous carve regions)
    const int ZN  = (int)(((char*)bucket_cnt - (char*)cnt) / 4) + 512;

    // --- graph preprocessing: degree+bucket hist, dinv, bucketed CSR ---
    zero_kernel<<<(ZN + 255) / 256, 256, 0, stream>>>(cnt, ZN);
    degbucket_kernel<<<PREB, 256, 0, stream>>>(e_dst, cnt, bucket_cnt, E);
    dinv_kernel<<<NB, 256, 0, stream>>>(cnt, dinv, N);
    bucket_scan_kernel<<<1, 512, 0, stream>>>(bucket_cnt, bucket_sta, bucket_cur, E);
    place_kernel<<<PREB, 256, 0, stream>>>(e_src, e_dst, bucket_cur, csr_tmp, E);
    bsort_kernel<<<NBUCK, 256, 0, stream>>>(bucket_sta, csr_tmp, row_ptr, csr_src, N, E);

    // --- L1 (128->16): GEMM first (narrow side), then aggregate+bias+relu ---
    gemm_kernel<128, 16, 16, 1, false><<<GB, 256, 0, stream>>>(x, W1, nullptr, bufA, N);
    agg_kernel<16, true><<<AGB, 256, 0, stream>>>(bufA, row_ptr, csr_src, dinv, b1, bufB, N);

    // --- L2 (16->32): aggregate first, then GEMM+bias+relu ---
    agg_kernel<16, false><<<AGB, 256, 0, stream>>>(bufB, row_ptr, csr_src, dinv, nullptr, bufA, N);
    gemm_kernel<16, 32, 32, 2, true><<<GB, 256, 0, stream>>>(bufA, W2, b2, bufB, N);

    // --- L3 (32->64) ---
    agg_kernel<32, false><<<AGB, 256, 0, stream>>>(bufB, row_ptr, csr_src, dinv, nullptr, bufA, N);
    gemm_kernel<32, 64, 64, 4, true><<<GB, 256, 0, stream>>>(bufA, W3, b3, bufB, N);

    // --- L4 (64->128): aggregate at width 64, then M-split GEMM ---
    agg_kernel<64, false><<<AGB, 256, 0, stream>>>(bufB, row_ptr, csr_src, dinv, nullptr, bufA, N);
    gemm_kernel<64, 128, 64, 4, true><<<GB * 2, 256, 0, stream>>>(bufA, W4, b4, bufB, N);

    // --- FC head ---
    gemm_kernel<128, 32, 32, 2, true><<<GB, 256, 0, stream>>>(bufB, Wf1, bf1, bufA, N);
    fc2_tanh_kernel<<<NB, 256, 0, stream>>>(bufA, Wf2, bf2, (float*)d_out, N);
}

// Round 7
// 447.133 us; speedup vs baseline: 1.3228x; 1.1289x over previous
//
#include <hip/hip_runtime.h>
#include <hip/hip_bf16.h>
#include <cmath>

// ---------------------------------------------------------------------------
// GCN: out = tanh(relu(relu(relu(relu(P(P(P(P(xW1+..)..) .. ))Wf1+bf1)Wf2+bf2
// P = D^-1/2 (A+I) D^-1/2 via CSR (dst-sorted) gather-sum, no float atomics.
// Associativity: aggregate at the *narrower* width of each layer.
// edge_index arrives as int32 (harness converts int64 inputs).
// R3: gemm<64,128,RT=8> spilled -> R4 M-split fixed.
// R4/R5: direct CSR fill: every 4B scatter writes back a whole line.
// R6: two-phase bucketed build (dst>>8, 391 buckets) fixed it; but per-node
// degree atomicAdd = 50MB of 32B-sector memory-side atomic traffic (70us).
// R7: degree is computed FREE inside bsort's LDS count (a node's edges all
// live in one bucket) -> dinv fused into bsort; hist kernel does bucket
// histogram only (LDS + 391 flush atomics/block). cnt array deleted.
// ---------------------------------------------------------------------------

#define NBUCK 391              // ceil(100000/256)
#define PREB  391              // ceil(E/4096) edge-phase blocks (16 edges/thread)

__global__ void zero_kernel(int* p, int n) {
    int i = blockIdx.x * 256 + threadIdx.x;
    if (i < n) p[i] = 0;
}

// bucket histogram only (16 edges/thread, LDS-aggregated)
__global__ __launch_bounds__(256) void hist_kernel(
        const int* __restrict__ dst, int* __restrict__ bucket_cnt, int E) {
    __shared__ int bh[NBUCK];
    const int t = threadIdx.x;
    for (int i = t; i < NBUCK; i += 256) bh[i] = 0;
    __syncthreads();
    const int base = blockIdx.x * 4096;
#pragma unroll
    for (int j = 0; j < 16; j++) {
        int e = base + j * 256 + t;
        if (e < E) atomicAdd(&bh[dst[e] >> 8], 1);
    }
    __syncthreads();
    for (int i = t; i < NBUCK; i += 256)
        if (bh[i]) atomicAdd(&bucket_cnt[i], bh[i]);
}

// exclusive scan of bucket_cnt[NBUCK] -> bucket_start (ro) + bucket_cursor (rw)
__global__ void bucket_scan_kernel(const int* __restrict__ bucket_cnt,
                                   int* __restrict__ bucket_start,
                                   int* __restrict__ bucket_cursor, int E) {
    __shared__ int s[512];
    int t = threadIdx.x;
    int v = (t < NBUCK) ? bucket_cnt[t] : 0;
    s[t] = v; __syncthreads();
    for (int off = 1; off < 512; off <<= 1) {
        int x = (t >= off) ? s[t - off] : 0;
        __syncthreads();
        s[t] += x;
        __syncthreads();
    }
    if (t < NBUCK) {
        int excl = s[t] - v;
        bucket_start[t] = excl;
        bucket_cursor[t] = excl;
    }
    if (t == 0) bucket_start[NBUCK] = E;
}

// Phase A: scatter packed edges into bucket-grouped csr_tmp.
// payload = (dst&255)<<17 | src  (src < 2^17). runs per (block,bucket) are
// contiguous -> write frontier 391 lines, L2-resident.
__global__ __launch_bounds__(256) void place_kernel(
        const int* __restrict__ src, const int* __restrict__ dst,
        int* __restrict__ bucket_cursor, int* __restrict__ csr_tmp, int E) {
    __shared__ int hist[NBUCK];
    const int t = threadIdx.x;
    for (int i = t; i < NBUCK; i += 256) hist[i] = 0;
    __syncthreads();
    const int base = blockIdx.x * 4096;
    int pay[16], rb[16];
#pragma unroll
    for (int j = 0; j < 16; j++) {
        int e = base + j * 256 + t;
        if (e < E) {
            int d = dst[e];
            int b = d >> 8;
            int r = atomicAdd(&hist[b], 1);       // r < 4096
            pay[j] = ((d & 255) << 17) | src[e];
            rb[j] = (r << 9) | b;                 // b < 512
        } else rb[j] = -1;
    }
    __syncthreads();
    for (int i = t; i < NBUCK; i += 256) {
        int h = hist[i];
        hist[i] = h ? atomicAdd(&bucket_cursor[i], h) : 0;
    }
    __syncthreads();
#pragma unroll
    for (int j = 0; j < 16; j++) {
        if (rb[j] >= 0) {
            int b = rb[j] & 511;
            int r = rb[j] >> 9;
            csr_tmp[hist[b] + r] = pay[j];
        }
    }
}

// Phase B: one block per bucket -> per-node CSR (row_ptr + csr_src) + dinv.
// All scatters confined to this bucket's ~16KB region. Node degree = LDS
// count c[t] (a node's edges all live in this bucket) -> dinv free here.
__global__ __launch_bounds__(256) void bsort_kernel(
        const int* __restrict__ bucket_start, const int* __restrict__ csr_tmp,
        int* __restrict__ row_ptr, int* __restrict__ csr_src,
        float* __restrict__ dinv, int N, int E) {
    __shared__ int c[256], s[256], cur[256];
    const int b = blockIdx.x;
    const int t = threadIdx.x;
    const int start = bucket_start[b];
    const int end = bucket_start[b + 1];
    c[t] = 0;
    __syncthreads();
    for (int e = start + t; e < end; e += 256)
        atomicAdd(&c[csr_tmp[e] >> 17], 1);
    __syncthreads();
    int v = c[t];
    s[t] = v; __syncthreads();
    for (int off = 1; off < 256; off <<= 1) {
        int x = (t >= off) ? s[t - off] : 0;
        __syncthreads();
        s[t] += x;
        __syncthreads();
    }
    int excl = s[t] - v;
    int node = (b << 8) + t;
    if (node < N) {
        row_ptr[node] = start + excl;
        dinv[node] = rsqrtf((float)v + 1.0f);
    }
    cur[t] = start + excl;
    if (b == NBUCK - 1 && t == 0) row_ptr[N] = E;
    __syncthreads();
    for (int e = start + t; e < end; e += 256) {
        int p = csr_tmp[e];
        int pos = atomicAdd(&cur[p >> 17], 1);
        csr_src[pos] = p & 0x1FFFF;
    }
}

// --- aggregation: out[i,:] = sum_e dinv[s]*dinv[i]*z[s,:] + dinv[i]^2*z[i,:]
template<int F, bool L1MODE>
__global__ __launch_bounds__(256) void agg_kernel(
        const float* __restrict__ z, const int* __restrict__ row_ptr,
        const int* __restrict__ csr_src, const float* __restrict__ dinv,
        const float* __restrict__ bias, float* __restrict__ out, int N) {
    constexpr int G = F / 4;       // lanes per row
    constexpr int S = 64 / G;      // edge slots per wave
    const int t = threadIdx.x;
    const int wave = t >> 6;
    const int lane = t & 63;
    const int slot = lane / G;
    const int f4 = lane % G;
    const int i = blockIdx.x * 4 + wave;
    if (i >= N) return;            // wave-uniform exit
    const int start = row_ptr[i];
    const int end = row_ptr[i + 1];
    const float di = dinv[i];
    float4 acc = {0.f, 0.f, 0.f, 0.f};
    for (int e = start + slot; e < end; e += S) {
        int s = csr_src[e];
        float w = dinv[s] * di;
        float4 zv = *(const float4*)&z[(size_t)s * F + f4 * 4];
        acc.x += w * zv.x; acc.y += w * zv.y; acc.z += w * zv.z; acc.w += w * zv.w;
    }
#pragma unroll
    for (int off = G; off < 64; off <<= 1) {
        acc.x += __shfl_xor(acc.x, off);
        acc.y += __shfl_xor(acc.y, off);
        acc.z += __shfl_xor(acc.z, off);
        acc.w += __shfl_xor(acc.w, off);
    }
    if (slot == 0) {
        float d2 = di * di;
        float4 zs = *(const float4*)&z[(size_t)i * F + f4 * 4];
        float4 r;
        r.x = acc.x + d2 * zs.x; r.y = acc.y + d2 * zs.y;
        r.z = acc.z + d2 * zs.z; r.w = acc.w + d2 * zs.w;
        if (L1MODE) {
            float4 bv = *(const float4*)&bias[f4 * 4];
            r.x = fmaxf(r.x + bv.x, 0.f); r.y = fmaxf(r.y + bv.y, 0.f);
            r.z = fmaxf(r.z + bv.z, 0.f); r.w = fmaxf(r.w + bv.w, 0.f);
        }
        *(float4*)&out[(size_t)i * F + f4 * 4] = r;
    }
}

// --- register-tiled GEMM: 64-row x MB-col tile per 256-thread block ---------
template<int K, int M, int MB, int RT, bool BIAS_RELU>
__global__ __launch_bounds__(256) void gemm_kernel(
        const float* __restrict__ A, const float* __restrict__ W,
        const float* __restrict__ bias, float* __restrict__ out, int N) {
    constexpr int CG = MB / 4;
    constexpr int TM = (256 / CG) * RT;
    constexpr int KP = K + 4;            // 2-way bank alias on As reads (free)
    constexpr int MSPLIT = M / MB;
    static_assert(TM == 64, "tile rows");
    __shared__ float As[TM * KP];
    __shared__ float Ws[K * MB];
    __shared__ float bs[MB];
    const int t = threadIdx.x;
    const int base = (blockIdx.x / MSPLIT) * TM;
    const int colb = (blockIdx.x % MSPLIT) * MB;
    const int rows_valid = min(TM, N - base);
    constexpr int KD4 = K / 4;
    for (int idx = t; idx < TM * KD4; idx += 256) {
        int row = idx / KD4, kc = idx % KD4;
        if (row < rows_valid)
            *(float4*)&As[row * KP + kc * 4] = *(const float4*)&A[(size_t)(base + row) * K + kc * 4];
    }
    constexpr int MD4 = MB / 4;
    for (int idx = t; idx < K * MD4; idx += 256) {
        int k = idx / MD4, c4 = idx % MD4;
        *(float4*)&Ws[k * MB + c4 * 4] = *(const float4*)&W[(size_t)k * M + colb + c4 * 4];
    }
    if (BIAS_RELU && t < MB) bs[t] = bias[colb + t];
    __syncthreads();

    const int tc = t % CG;
    const int r0 = (t / CG) * RT;
    const int c0 = tc * 4;
    float4 acc[RT];
#pragma unroll
    for (int r = 0; r < RT; r++) acc[r] = {0.f, 0.f, 0.f, 0.f};

#pragma unroll 4
    for (int k = 0; k < K; k += 4) {
        float4 w0 = *(const float4*)&Ws[(k + 0) * MB + c0];
        float4 w1 = *(const float4*)&Ws[(k + 1) * MB + c0];
        float4 w2 = *(const float4*)&Ws[(k + 2) * MB + c0];
        float4 w3 = *(const float4*)&Ws[(k + 3) * MB + c0];
#pragma unroll
        for (int r = 0; r < RT; r++) {
            float4 av = *(const float4*)&As[(r0 + r) * KP + k];
            acc[r].x += av.x * w0.x + av.y * w1.x + av.z * w2.x + av.w * w3.x;
            acc[r].y += av.x * w0.y + av.y * w1.y + av.z * w2.y + av.w * w3.y;
            acc[r].z += av.x * w0.z + av.y * w1.z + av.z * w2.z + av.w * w3.z;
            acc[r].w += av.x * w0.w + av.y * w1.w + av.z * w2.w + av.w * w3.w;
        }
    }
#pragma unroll
    for (int r = 0; r < RT; r++) {
        int row = base + r0 + r;
        if (row < N) {
            float4 v = acc[r];
            if (BIAS_RELU) {
                float4 bv = *(const float4*)&bs[c0];
                v.x = fmaxf(v.x + bv.x, 0.f); v.y = fmaxf(v.y + bv.y, 0.f);
                v.z = fmaxf(v.z + bv.z, 0.f); v.w = fmaxf(v.w + bv.w, 0.f);
            }
            *(float4*)&out[(size_t)row * M + colb + c0] = v;
        }
    }
}

// --- final FC: K=32, M=10, tanh --------------------------------------------
__global__ __launch_bounds__(256) void fc2_tanh_kernel(
        const float* __restrict__ A, const float* __restrict__ W,
        const float* __restrict__ bias, float* __restrict__ out, int N) {
    __shared__ float wt[10][36];
    __shared__ float bs[10];
    int t = threadIdx.x;
    for (int idx = t; idx < 320; idx += 256) { int k = idx / 10, m = idx % 10; wt[m][k] = W[idx]; }
    if (t < 10) bs[t] = bias[t];
    __syncthreads();
    int row = blockIdx.x * 256 + t;
    if (row >= N) return;
    float a[32];
    const float4* ap = (const float4*)(A + (size_t)row * 32);
#pragma unroll
    for (int j = 0; j < 8; j++) {
        float4 v = ap[j];
        a[4 * j] = v.x; a[4 * j + 1] = v.y; a[4 * j + 2] = v.z; a[4 * j + 3] = v.w;
    }
#pragma unroll
    for (int m = 0; m < 10; m++) {
        float acc = bs[m];
#pragma unroll
        for (int k = 0; k < 32; k++) acc += a[k] * wt[m][k];
        out[(size_t)row * 10 + m] = tanhf(acc);
    }
}

extern "C" void kernel_launch(void* const* d_in, const int* in_sizes, int n_in,
                              void* d_out, int out_size, void* d_ws, size_t ws_size,
                              hipStream_t stream) {
    const float* x   = (const float*)d_in[0];
    const int*   ei  = (const int*)d_in[1];     // int32 on device
    const float* W1  = (const float*)d_in[2];
    const float* b1  = (const float*)d_in[3];
    const float* W2  = (const float*)d_in[4];
    const float* b2  = (const float*)d_in[5];
    const float* W3  = (const float*)d_in[6];
    const float* b3  = (const float*)d_in[7];
    const float* W4  = (const float*)d_in[8];
    const float* b4  = (const float*)d_in[9];
    const float* Wf1 = (const float*)d_in[10];
    const float* bf1 = (const float*)d_in[11];
    const float* Wf2 = (const float*)d_in[12];
    const float* bf2 = (const float*)d_in[13];

    const int N = in_sizes[0] / 128;   // 100000
    const int E = in_sizes[1] / 2;     // 1600000
    const int* e_src = ei;
    const int* e_dst = ei + E;

    char* p = (char*)d_ws;
    auto carve = [&](size_t bytes) -> void* {
        void* r = (void*)p;
        p += (bytes + 255) & ~(size_t)255;
        return r;
    };
    int*   bucket_cnt = (int*)carve(512 * 4);
    int*   bucket_sta = (int*)carve(512 * 4);
    int*   bucket_cur = (int*)carve(512 * 4);
    float* dinv       = (float*)carve((size_t)N * 4);
    int*   row_ptr    = (int*)carve((size_t)(N + 1) * 4);
    int*   csr_tmp    = (int*)carve((size_t)E * 4);
    int*   csr_src    = (int*)carve((size_t)E * 4);
    float* bufA       = (float*)carve((size_t)N * 64 * 4);
    float* bufB       = (float*)carve((size_t)N * 128 * 4);

    const int NB  = (N + 255) / 256;   // 391
    const int AGB = (N + 3) / 4;
    const int GB  = (N + 63) / 64;     // 1563 row-blocks

    // --- graph preprocessing: bucket hist, scan, place, bsort(+dinv) ---
    zero_kernel<<<2, 256, 0, stream>>>(bucket_cnt, 512);
    hist_kernel<<<PREB, 256, 0, stream>>>(e_dst, bucket_cnt, E);
    bucket_scan_kernel<<<1, 512, 0, stream>>>(bucket_cnt, bucket_sta, bucket_cur, E);
    place_kernel<<<PREB, 256, 0, stream>>>(e_src, e_dst, bucket_cur, csr_tmp, E);
    bsort_kernel<<<NBUCK, 256, 0, stream>>>(bucket_sta, csr_tmp, row_ptr, csr_src, dinv, N, E);

    // --- L1 (128->16): GEMM first (narrow side), then aggregate+bias+relu ---
    gemm_kernel<128, 16, 16, 1, false><<<GB, 256, 0, stream>>>(x, W1, nullptr, bufA, N);
    agg_kernel<16, true><<<AGB, 256, 0, stream>>>(bufA, row_ptr, csr_src, dinv, b1, bufB, N);

    // --- L2 (16->32): aggregate first, then GEMM+bias+relu ---
    agg_kernel<16, false><<<AGB, 256, 0, stream>>>(bufB, row_ptr, csr_src, dinv, nullptr, bufA, N);
    gemm_kernel<16, 32, 32, 2, true><<<GB, 256, 0, stream>>>(bufA, W2, b2, bufB, N);

    // --- L3 (32->64) ---
    agg_kernel<32, false><<<AGB, 256, 0, stream>>>(bufB, row_ptr, csr_src, dinv, nullptr, bufA, N);
    gemm_kernel<32, 64, 64, 4, true><<<GB, 256, 0, stream>>>(bufA, W3, b3, bufB, N);

    // --- L4 (64->128): aggregate at width 64, then M-split GEMM ---
    agg_kernel<64, false><<<AGB, 256, 0, stream>>>(bufB, row_ptr, csr_src, dinv, nullptr, bufA, N);
    gemm_kernel<64, 128, 64, 4, true><<<GB * 2, 256, 0, stream>>>(bufA, W4, b4, bufB, N);

    // --- FC head ---
    gemm_kernel<128, 32, 32, 2, true><<<GB, 256, 0, stream>>>(bufB, Wf1, bf1, bufA, N);
    fc2_tanh_kernel<<<NB, 256, 0, stream>>>(bufA, Wf2, bf2, (float*)d_out, N);
}

// Round 8
// 439.715 us; speedup vs baseline: 1.3451x; 1.0169x over previous
//
#include <hip/hip_runtime.h>
#include <hip/hip_bf16.h>
#include <cmath>

// ---------------------------------------------------------------------------
// GCN: out = tanh(relu(relu(relu(relu(P(P(P(P(xW1+..)..) .. ))Wf1+bf1)Wf2+bf2
// P = D^-1/2 (A+I) D^-1/2 via CSR (dst-sorted) gather-sum, no float atomics.
// Associativity: aggregate at the *narrower* width of each layer.
// edge_index arrives as int32 (harness converts int64 inputs).
// R3: gemm<64,128,RT=8> spilled -> R4 M-split fixed.
// R4/R5: direct CSR fill: every 4B scatter writes back a whole line.
// R6: two-phase bucketed build (dst>>8, 391 buckets) fixed it.
// R7: degree fused into bsort's LDS count; per-node degree atomics deleted.
// R8: agg was latency-bound (BW 41%, VALU 20%, occ 70%): 2-deep dependent
// gather chain with only S=4 slot-chains/wave at F=64. Unroll edge loop x4
// (4/2/1 cascade) -> 16 outstanding gathers/wave.
// ---------------------------------------------------------------------------

#define NBUCK 391              // ceil(100000/256)
#define PREB  391              // ceil(E/4096) edge-phase blocks (16 edges/thread)

__global__ void zero_kernel(int* p, int n) {
    int i = blockIdx.x * 256 + threadIdx.x;
    if (i < n) p[i] = 0;
}

// bucket histogram only (16 edges/thread, LDS-aggregated)
__global__ __launch_bounds__(256) void hist_kernel(
        const int* __restrict__ dst, int* __restrict__ bucket_cnt, int E) {
    __shared__ int bh[NBUCK];
    const int t = threadIdx.x;
    for (int i = t; i < NBUCK; i += 256) bh[i] = 0;
    __syncthreads();
    const int base = blockIdx.x * 4096;
#pragma unroll
    for (int j = 0; j < 16; j++) {
        int e = base + j * 256 + t;
        if (e < E) atomicAdd(&bh[dst[e] >> 8], 1);
    }
    __syncthreads();
    for (int i = t; i < NBUCK; i += 256)
        if (bh[i]) atomicAdd(&bucket_cnt[i], bh[i]);
}

// exclusive scan of bucket_cnt[NBUCK] -> bucket_start (ro) + bucket_cursor (rw)
__global__ void bucket_scan_kernel(const int* __restrict__ bucket_cnt,
                                   int* __restrict__ bucket_start,
                                   int* __restrict__ bucket_cursor, int E) {
    __shared__ int s[512];
    int t = threadIdx.x;
    int v = (t < NBUCK) ? bucket_cnt[t] : 0;
    s[t] = v; __syncthreads();
    for (int off = 1; off < 512; off <<= 1) {
        int x = (t >= off) ? s[t - off] : 0;
        __syncthreads();
        s[t] += x;
        __syncthreads();
    }
    if (t < NBUCK) {
        int excl = s[t] - v;
        bucket_start[t] = excl;
        bucket_cursor[t] = excl;
    }
    if (t == 0) bucket_start[NBUCK] = E;
}

// Phase A: scatter packed edges into bucket-grouped csr_tmp.
// payload = (dst&255)<<17 | src  (src < 2^17). runs per (block,bucket) are
// contiguous -> write frontier 391 lines, L2-resident.
__global__ __launch_bounds__(256) void place_kernel(
        const int* __restrict__ src, const int* __restrict__ dst,
        int* __restrict__ bucket_cursor, int* __restrict__ csr_tmp, int E) {
    __shared__ int hist[NBUCK];
    const int t = threadIdx.x;
    for (int i = t; i < NBUCK; i += 256) hist[i] = 0;
    __syncthreads();
    const int base = blockIdx.x * 4096;
    int pay[16], rb[16];
#pragma unroll
    for (int j = 0; j < 16; j++) {
        int e = base + j * 256 + t;
        if (e < E) {
            int d = dst[e];
            int b = d >> 8;
            int r = atomicAdd(&hist[b], 1);       // r < 4096
            pay[j] = ((d & 255) << 17) | src[e];
            rb[j] = (r << 9) | b;                 // b < 512
        } else rb[j] = -1;
    }
    __syncthreads();
    for (int i = t; i < NBUCK; i += 256) {
        int h = hist[i];
        hist[i] = h ? atomicAdd(&bucket_cursor[i], h) : 0;
    }
    __syncthreads();
#pragma unroll
    for (int j = 0; j < 16; j++) {
        if (rb[j] >= 0) {
            int b = rb[j] & 511;
            int r = rb[j] >> 9;
            csr_tmp[hist[b] + r] = pay[j];
        }
    }
}

// Phase B: one block per bucket -> per-node CSR (row_ptr + csr_src) + dinv.
// All scatters confined to this bucket's ~16KB region. Node degree = LDS
// count c[t] (a node's edges all live in this bucket) -> dinv free here.
__global__ __launch_bounds__(256) void bsort_kernel(
        const int* __restrict__ bucket_start, const int* __restrict__ csr_tmp,
        int* __restrict__ row_ptr, int* __restrict__ csr_src,
        float* __restrict__ dinv, int N, int E) {
    __shared__ int c[256], s[256], cur[256];
    const int b = blockIdx.x;
    const int t = threadIdx.x;
    const int start = bucket_start[b];
    const int end = bucket_start[b + 1];
    c[t] = 0;
    __syncthreads();
    for (int e = start + t; e < end; e += 256)
        atomicAdd(&c[csr_tmp[e] >> 17], 1);
    __syncthreads();
    int v = c[t];
    s[t] = v; __syncthreads();
    for (int off = 1; off < 256; off <<= 1) {
        int x = (t >= off) ? s[t - off] : 0;
        __syncthreads();
        s[t] += x;
        __syncthreads();
    }
    int excl = s[t] - v;
    int node = (b << 8) + t;
    if (node < N) {
        row_ptr[node] = start + excl;
        dinv[node] = rsqrtf((float)v + 1.0f);
    }
    cur[t] = start + excl;
    if (b == NBUCK - 1 && t == 0) row_ptr[N] = E;
    __syncthreads();
    for (int e = start + t; e < end; e += 256) {
        int p = csr_tmp[e];
        int pos = atomicAdd(&cur[p >> 17], 1);
        csr_src[pos] = p & 0x1FFFF;
    }
}

// --- aggregation: out[i,:] = sum_e dinv[s]*dinv[i]*z[s,:] + dinv[i]^2*z[i,:]
// one wave per node; G=F/4 lanes per edge-slot read the row as float4;
// edge loop unrolled 4/2/1 to keep up to 16 gathers in flight per wave.
template<int F, bool L1MODE>
__global__ __launch_bounds__(256) void agg_kernel(
        const float* __restrict__ z, const int* __restrict__ row_ptr,
        const int* __restrict__ csr_src, const float* __restrict__ dinv,
        const float* __restrict__ bias, float* __restrict__ out, int N) {
    constexpr int G = F / 4;       // lanes per row
    constexpr int S = 64 / G;      // edge slots per wave
    const int t = threadIdx.x;
    const int wave = t >> 6;
    const int lane = t & 63;
    const int slot = lane / G;
    const int f4 = lane % G;
    const int i = blockIdx.x * 4 + wave;
    if (i >= N) return;            // wave-uniform exit
    const int start = row_ptr[i];
    const int end = row_ptr[i + 1];
    const float di = dinv[i];
    float4 acc = {0.f, 0.f, 0.f, 0.f};
    int e = start + slot;
    // U=4 block: 4 independent csr->z chains in flight per slot
    while (e + 3 * S < end) {
        int s0 = csr_src[e];
        int s1 = csr_src[e + S];
        int s2 = csr_src[e + 2 * S];
        int s3 = csr_src[e + 3 * S];
        float w0 = dinv[s0], w1 = dinv[s1], w2 = dinv[s2], w3 = dinv[s3];
        float4 z0 = *(const float4*)&z[(size_t)s0 * F + f4 * 4];
        float4 z1 = *(const float4*)&z[(size_t)s1 * F + f4 * 4];
        float4 z2 = *(const float4*)&z[(size_t)s2 * F + f4 * 4];
        float4 z3 = *(const float4*)&z[(size_t)s3 * F + f4 * 4];
        w0 *= di; w1 *= di; w2 *= di; w3 *= di;
        acc.x += w0 * z0.x; acc.y += w0 * z0.y; acc.z += w0 * z0.z; acc.w += w0 * z0.w;
        acc.x += w1 * z1.x; acc.y += w1 * z1.y; acc.z += w1 * z1.z; acc.w += w1 * z1.w;
        acc.x += w2 * z2.x; acc.y += w2 * z2.y; acc.z += w2 * z2.z; acc.w += w2 * z2.w;
        acc.x += w3 * z3.x; acc.y += w3 * z3.y; acc.z += w3 * z3.z; acc.w += w3 * z3.w;
        e += 4 * S;
    }
    if (e + S < end) {             // U=2 block
        int s0 = csr_src[e];
        int s1 = csr_src[e + S];
        float w0 = dinv[s0], w1 = dinv[s1];
        float4 z0 = *(const float4*)&z[(size_t)s0 * F + f4 * 4];
        float4 z1 = *(const float4*)&z[(size_t)s1 * F + f4 * 4];
        w0 *= di; w1 *= di;
        acc.x += w0 * z0.x; acc.y += w0 * z0.y; acc.z += w0 * z0.z; acc.w += w0 * z0.w;
        acc.x += w1 * z1.x; acc.y += w1 * z1.y; acc.z += w1 * z1.z; acc.w += w1 * z1.w;
        e += 2 * S;
    }
    if (e < end) {                 // tail
        int s0 = csr_src[e];
        float w0 = dinv[s0] * di;
        float4 z0 = *(const float4*)&z[(size_t)s0 * F + f4 * 4];
        acc.x += w0 * z0.x; acc.y += w0 * z0.y; acc.z += w0 * z0.z; acc.w += w0 * z0.w;
    }
#pragma unroll
    for (int off = G; off < 64; off <<= 1) {
        acc.x += __shfl_xor(acc.x, off);
        acc.y += __shfl_xor(acc.y, off);
        acc.z += __shfl_xor(acc.z, off);
        acc.w += __shfl_xor(acc.w, off);
    }
    if (slot == 0) {
        float d2 = di * di;
        float4 zs = *(const float4*)&z[(size_t)i * F + f4 * 4];
        float4 r;
        r.x = acc.x + d2 * zs.x; r.y = acc.y + d2 * zs.y;
        r.z = acc.z + d2 * zs.z; r.w = acc.w + d2 * zs.w;
        if (L1MODE) {
            float4 bv = *(const float4*)&bias[f4 * 4];
            r.x = fmaxf(r.x + bv.x, 0.f); r.y = fmaxf(r.y + bv.y, 0.f);
            r.z = fmaxf(r.z + bv.z, 0.f); r.w = fmaxf(r.w + bv.w, 0.f);
        }
        *(float4*)&out[(size_t)i * F + f4 * 4] = r;
    }
}

// --- register-tiled GEMM: 64-row x MB-col tile per 256-thread block ---------
template<int K, int M, int MB, int RT, bool BIAS_RELU>
__global__ __launch_bounds__(256) void gemm_kernel(
        const float* __restrict__ A, const float* __restrict__ W,
        const float* __restrict__ bias, float* __restrict__ out, int N) {
    constexpr int CG = MB / 4;
    constexpr int TM = (256 / CG) * RT;
    constexpr int KP = K + 4;            // 2-way bank alias on As reads (free)
    constexpr int MSPLIT = M / MB;
    static_assert(TM == 64, "tile rows");
    __shared__ float As[TM * KP];
    __shared__ float Ws[K * MB];
    __shared__ float bs[MB];
    const int t = threadIdx.x;
    const int base = (blockIdx.x / MSPLIT) * TM;
    const int colb = (blockIdx.x % MSPLIT) * MB;
    const int rows_valid = min(TM, N - base);
    constexpr int KD4 = K / 4;
    for (int idx = t; idx < TM * KD4; idx += 256) {
        int row = idx / KD4, kc = idx % KD4;
        if (row < rows_valid)
            *(float4*)&As[row * KP + kc * 4] = *(const float4*)&A[(size_t)(base + row) * K + kc * 4];
    }
    constexpr int MD4 = MB / 4;
    for (int idx = t; idx < K * MD4; idx += 256) {
        int k = idx / MD4, c4 = idx % MD4;
        *(float4*)&Ws[k * MB + c4 * 4] = *(const float4*)&W[(size_t)k * M + colb + c4 * 4];
    }
    if (BIAS_RELU && t < MB) bs[t] = bias[colb + t];
    __syncthreads();

    const int tc = t % CG;
    const int r0 = (t / CG) * RT;
    const int c0 = tc * 4;
    float4 acc[RT];
#pragma unroll
    for (int r = 0; r < RT; r++) acc[r] = {0.f, 0.f, 0.f, 0.f};

#pragma unroll 4
    for (int k = 0; k < K; k += 4) {
        float4 w0 = *(const float4*)&Ws[(k + 0) * MB + c0];
        float4 w1 = *(const float4*)&Ws[(k + 1) * MB + c0];
        float4 w2 = *(const float4*)&Ws[(k + 2) * MB + c0];
        float4 w3 = *(const float4*)&Ws[(k + 3) * MB + c0];
#pragma unroll
        for (int r = 0; r < RT; r++) {
            float4 av = *(const float4*)&As[(r0 + r) * KP + k];
            acc[r].x += av.x * w0.x + av.y * w1.x + av.z * w2.x + av.w * w3.x;
            acc[r].y += av.x * w0.y + av.y * w1.y + av.z * w2.y + av.w * w3.y;
            acc[r].z += av.x * w0.z + av.y * w1.z + av.z * w2.z + av.w * w3.z;
            acc[r].w += av.x * w0.w + av.y * w1.w + av.z * w2.w + av.w * w3.w;
        }
    }
#pragma unroll
    for (int r = 0; r < RT; r++) {
        int row = base + r0 + r;
        if (row < N) {
            float4 v = acc[r];
            if (BIAS_RELU) {
                float4 bv = *(const float4*)&bs[c0];
                v.x = fmaxf(v.x + bv.x, 0.f); v.y = fmaxf(v.y + bv.y, 0.f);
                v.z = fmaxf(v.z + bv.z, 0.f); v.w = fmaxf(v.w + bv.w, 0.f);
            }
            *(float4*)&out[(size_t)row * M + colb + c0] = v;
        }
    }
}

// --- final FC: K=32, M=10, tanh --------------------------------------------
__global__ __launch_bounds__(256) void fc2_tanh_kernel(
        const float* __restrict__ A, const float* __restrict__ W,
        const float* __restrict__ bias, float* __restrict__ out, int N) {
    __shared__ float wt[10][36];
    __shared__ float bs[10];
    int t = threadIdx.x;
    for (int idx = t; idx < 320; idx += 256) { int k = idx / 10, m = idx % 10; wt[m][k] = W[idx]; }
    if (t < 10) bs[t] = bias[t];
    __syncthreads();
    int row = blockIdx.x * 256 + t;
    if (row >= N) return;
    float a[32];
    const float4* ap = (const float4*)(A + (size_t)row * 32);
#pragma unroll
    for (int j = 0; j < 8; j++) {
        float4 v = ap[j];
        a[4 * j] = v.x; a[4 * j + 1] = v.y; a[4 * j + 2] = v.z; a[4 * j + 3] = v.w;
    }
#pragma unroll
    for (int m = 0; m < 10; m++) {
        float acc = bs[m];
#pragma unroll
        for (int k = 0; k < 32; k++) acc += a[k] * wt[m][k];
        out[(size_t)row * 10 + m] = tanhf(acc);
    }
}

extern "C" void kernel_launch(void* const* d_in, const int* in_sizes, int n_in,
                              void* d_out, int out_size, void* d_ws, size_t ws_size,
                              hipStream_t stream) {
    const float* x   = (const float*)d_in[0];
    const int*   ei  = (const int*)d_in[1];     // int32 on device
    const float* W1  = (const float*)d_in[2];
    const float* b1  = (const float*)d_in[3];
    const float* W2  = (const float*)d_in[4];
    const float* b2  = (const float*)d_in[5];
    const float* W3  = (const float*)d_in[6];
    const float* b3  = (const float*)d_in[7];
    const float* W4  = (const float*)d_in[8];
    const float* b4  = (const float*)d_in[9];
    const float* Wf1 = (const float*)d_in[10];
    const float* bf1 = (const float*)d_in[11];
    const float* Wf2 = (const float*)d_in[12];
    const float* bf2 = (const float*)d_in[13];

    const int N = in_sizes[0] / 128;   // 100000
    const int E = in_sizes[1] / 2;     // 1600000
    const int* e_src = ei;
    const int* e_dst = ei + E;

    char* p = (char*)d_ws;
    auto carve = [&](size_t bytes) -> void* {
        void* r = (void*)p;
        p += (bytes + 255) & ~(size_t)255;
        return r;
    };
    int*   bucket_cnt = (int*)carve(512 * 4);
    int*   bucket_sta = (int*)carve(512 * 4);
    int*   bucket_cur = (int*)carve(512 * 4);
    float* dinv       = (float*)carve((size_t)N * 4);
    int*   row_ptr    = (int*)carve((size_t)(N + 1) * 4);
    int*   csr_tmp    = (int*)carve((size_t)E * 4);
    int*   csr_src    = (int*)carve((size_t)E * 4);
    float* bufA       = (float*)carve((size_t)N * 64 * 4);
    float* bufB       = (float*)carve((size_t)N * 128 * 4);

    const int NB  = (N + 255) / 256;   // 391
    const int AGB = (N + 3) / 4;
    const int GB  = (N + 63) / 64;     // 1563 row-blocks

    // --- graph preprocessing: bucket hist, scan, place, bsort(+dinv) ---
    zero_kernel<<<2, 256, 0, stream>>>(bucket_cnt, 512);
    hist_kernel<<<PREB, 256, 0, stream>>>(e_dst, bucket_cnt, E);
    bucket_scan_kernel<<<1, 512, 0, stream>>>(bucket_cnt, bucket_sta, bucket_cur, E);
    place_kernel<<<PREB, 256, 0, stream>>>(e_src, e_dst, bucket_cur, csr_tmp, E);
    bsort_kernel<<<NBUCK, 256, 0, stream>>>(bucket_sta, csr_tmp, row_ptr, csr_src, dinv, N, E);

    // --- L1 (128->16): GEMM first (narrow side), then aggregate+bias+relu ---
    gemm_kernel<128, 16, 16, 1, false><<<GB, 256, 0, stream>>>(x, W1, nullptr, bufA, N);
    agg_kernel<16, true><<<AGB, 256, 0, stream>>>(bufA, row_ptr, csr_src, dinv, b1, bufB, N);

    // --- L2 (16->32): aggregate first, then GEMM+bias+relu ---
    agg_kernel<16, false><<<AGB, 256, 0, stream>>>(bufB, row_ptr, csr_src, dinv, nullptr, bufA, N);
    gemm_kernel<16, 32, 32, 2, true><<<GB, 256, 0, stream>>>(bufA, W2, b2, bufB, N);

    // --- L3 (32->64) ---
    agg_kernel<32, false><<<AGB, 256, 0, stream>>>(bufB, row_ptr, csr_src, dinv, nullptr, bufA, N);
    gemm_kernel<32, 64, 64, 4, true><<<GB, 256, 0, stream>>>(bufA, W3, b3, bufB, N);

    // --- L4 (64->128): aggregate at width 64, then M-split GEMM ---
    agg_kernel<64, false><<<AGB, 256, 0, stream>>>(bufB, row_ptr, csr_src, dinv, nullptr, bufA, N);
    gemm_kernel<64, 128, 64, 4, true><<<GB * 2, 256, 0, stream>>>(bufA, W4, b4, bufB, N);

    // --- FC head ---
    gemm_kernel<128, 32, 32, 2, true><<<GB, 256, 0, stream>>>(bufB, Wf1, bf1, bufA, N);
    fc2_tanh_kernel<<<NB, 256, 0, stream>>>(bufA, Wf2, bf2, (float*)d_out, N);
}

// Round 9
// 416.335 us; speedup vs baseline: 1.4206x; 1.0562x over previous
//
#include <hip/hip_runtime.h>
#include <hip/hip_bf16.h>
#include <cmath>

// ---------------------------------------------------------------------------
// GCN: out = tanh(relu(relu(relu(relu(P(P(P(P(xW1+..)..) .. ))Wf1+bf1)Wf2+bf2
// P = D^-1/2 (A+I) D^-1/2 via CSR (dst-sorted) gather-sum, no float atomics.
// Associativity: aggregate at the *narrower* width of each layer.
// R6: bucketed CSR build (write-frontier fits L2). R7: dinv fused into bsort.
// R8: agg MLP unroll x4 -> only 10%; agg is FABRIC-BW bound (~3.1 TB/s):
// per-XCD each z row requested ~2x -> miss ~(1-e^-2)/2 = 47% = observed.
// R9: cut bytes. (a) prescale zs=dinv*z at producers (agg inputs are
// single-consumer) -> out=dinv[i]*(sum zs[src]+zs[i]); kills per-edge dinv
// gather. (b) bf16 transport for z2 (32w) and z3 (64w) gathers, fp32 accum;
// RTN rounding. L1/L2 stay fp32 for accuracy margin.
// ---------------------------------------------------------------------------

#define NBUCK 391              // ceil(100000/256)
#define PREB  391              // ceil(E/4096) edge-phase blocks (16 edges/thread)

__device__ __forceinline__ unsigned short f_to_bf(float v) {
    unsigned u = __float_as_uint(v);
    return (unsigned short)((u + 0x7FFF + ((u >> 16) & 1)) >> 16);   // RTN-even
}
__device__ __forceinline__ float bf_to_f(unsigned short v) {
    return __uint_as_float((unsigned)v << 16);
}

__global__ void zero_kernel(int* p, int n) {
    int i = blockIdx.x * 256 + threadIdx.x;
    if (i < n) p[i] = 0;
}

// bucket histogram only (16 edges/thread, LDS-aggregated)
__global__ __launch_bounds__(256) void hist_kernel(
        const int* __restrict__ dst, int* __restrict__ bucket_cnt, int E) {
    __shared__ int bh[NBUCK];
    const int t = threadIdx.x;
    for (int i = t; i < NBUCK; i += 256) bh[i] = 0;
    __syncthreads();
    const int base = blockIdx.x * 4096;
#pragma unroll
    for (int j = 0; j < 16; j++) {
        int e = base + j * 256 + t;
        if (e < E) atomicAdd(&bh[dst[e] >> 8], 1);
    }
    __syncthreads();
    for (int i = t; i < NBUCK; i += 256)
        if (bh[i]) atomicAdd(&bucket_cnt[i], bh[i]);
}

// exclusive scan of bucket_cnt[NBUCK] -> bucket_start (ro) + bucket_cursor (rw)
__global__ void bucket_scan_kernel(const int* __restrict__ bucket_cnt,
                                   int* __restrict__ bucket_start,
                                   int* __restrict__ bucket_cursor, int E) {
    __shared__ int s[512];
    int t = threadIdx.x;
    int v = (t < NBUCK) ? bucket_cnt[t] : 0;
    s[t] = v; __syncthreads();
    for (int off = 1; off < 512; off <<= 1) {
        int x = (t >= off) ? s[t - off] : 0;
        __syncthreads();
        s[t] += x;
        __syncthreads();
    }
    if (t < NBUCK) {
        int excl = s[t] - v;
        bucket_start[t] = excl;
        bucket_cursor[t] = excl;
    }
    if (t == 0) bucket_start[NBUCK] = E;
}

// Phase A: scatter packed edges into bucket-grouped csr_tmp.
// payload = (dst&255)<<17 | src  (src < 2^17). runs per (block,bucket) are
// contiguous -> write frontier 391 lines, L2-resident.
__global__ __launch_bounds__(256) void place_kernel(
        const int* __restrict__ src, const int* __restrict__ dst,
        int* __restrict__ bucket_cursor, int* __restrict__ csr_tmp, int E) {
    __shared__ int hist[NBUCK];
    const int t = threadIdx.x;
    for (int i = t; i < NBUCK; i += 256) hist[i] = 0;
    __syncthreads();
    const int base = blockIdx.x * 4096;
    int pay[16], rb[16];
#pragma unroll
    for (int j = 0; j < 16; j++) {
        int e = base + j * 256 + t;
        if (e < E) {
            int d = dst[e];
            int b = d >> 8;
            int r = atomicAdd(&hist[b], 1);       // r < 4096
            pay[j] = ((d & 255) << 17) | src[e];
            rb[j] = (r << 9) | b;                 // b < 512
        } else rb[j] = -1;
    }
    __syncthreads();
    for (int i = t; i < NBUCK; i += 256) {
        int h = hist[i];
        hist[i] = h ? atomicAdd(&bucket_cursor[i], h) : 0;
    }
    __syncthreads();
#pragma unroll
    for (int j = 0; j < 16; j++) {
        if (rb[j] >= 0) {
            int b = rb[j] & 511;
            int r = rb[j] >> 9;
            csr_tmp[hist[b] + r] = pay[j];
        }
    }
}

// Phase B: one block per bucket -> per-node CSR (row_ptr + csr_src) + dinv.
__global__ __launch_bounds__(256) void bsort_kernel(
        const int* __restrict__ bucket_start, const int* __restrict__ csr_tmp,
        int* __restrict__ row_ptr, int* __restrict__ csr_src,
        float* __restrict__ dinv, int N, int E) {
    __shared__ int c[256], s[256], cur[256];
    const int b = blockIdx.x;
    const int t = threadIdx.x;
    const int start = bucket_start[b];
    const int end = bucket_start[b + 1];
    c[t] = 0;
    __syncthreads();
    for (int e = start + t; e < end; e += 256)
        atomicAdd(&c[csr_tmp[e] >> 17], 1);
    __syncthreads();
    int v = c[t];
    s[t] = v; __syncthreads();
    for (int off = 1; off < 256; off <<= 1) {
        int x = (t >= off) ? s[t - off] : 0;
        __syncthreads();
        s[t] += x;
        __syncthreads();
    }
    int excl = s[t] - v;
    int node = (b << 8) + t;
    if (node < N) {
        row_ptr[node] = start + excl;
        dinv[node] = rsqrtf((float)v + 1.0f);
    }
    cur[t] = start + excl;
    if (b == NBUCK - 1 && t == 0) row_ptr[N] = E;
    __syncthreads();
    for (int e = start + t; e < end; e += 256) {
        int p = csr_tmp[e];
        int pos = atomicAdd(&cur[p >> 17], 1);
        csr_src[pos] = p & 0x1FFFF;
    }
}

// --- fp32 aggregation over PRESCALED input zs = dinv*z ----------------------
// out[i] = dinv[i] * (sum_e zs[src_e] + zs[i]); optional bias+relu; optional
// output prescale (when the consumer is another agg).
template<int F, bool L1MODE, bool PRESCALE_OUT>
__global__ __launch_bounds__(256) void agg_kernel(
        const float* __restrict__ z, const int* __restrict__ row_ptr,
        const int* __restrict__ csr_src, const float* __restrict__ dinv,
        const float* __restrict__ bias, float* __restrict__ out, int N) {
    constexpr int G = F / 4;       // lanes per row
    constexpr int S = 64 / G;      // edge slots per wave
    const int t = threadIdx.x;
    const int wave = t >> 6;
    const int lane = t & 63;
    const int slot = lane / G;
    const int f4 = lane % G;
    const int i = blockIdx.x * 4 + wave;
    if (i >= N) return;            // wave-uniform exit
    const int start = row_ptr[i];
    const int end = row_ptr[i + 1];
    float4 acc = {0.f, 0.f, 0.f, 0.f};
    int e = start + slot;
    while (e + 3 * S < end) {      // U=4: 4 independent chains per slot
        int s0 = csr_src[e];
        int s1 = csr_src[e + S];
        int s2 = csr_src[e + 2 * S];
        int s3 = csr_src[e + 3 * S];
        float4 z0 = *(const float4*)&z[(size_t)s0 * F + f4 * 4];
        float4 z1 = *(const float4*)&z[(size_t)s1 * F + f4 * 4];
        float4 z2 = *(const float4*)&z[(size_t)s2 * F + f4 * 4];
        float4 z3 = *(const float4*)&z[(size_t)s3 * F + f4 * 4];
        acc.x += z0.x + z1.x + z2.x + z3.x;
        acc.y += z0.y + z1.y + z2.y + z3.y;
        acc.z += z0.z + z1.z + z2.z + z3.z;
        acc.w += z0.w + z1.w + z2.w + z3.w;
        e += 4 * S;
    }
    if (e + S < end) {             // U=2
        int s0 = csr_src[e];
        int s1 = csr_src[e + S];
        float4 z0 = *(const float4*)&z[(size_t)s0 * F + f4 * 4];
        float4 z1 = *(const float4*)&z[(size_t)s1 * F + f4 * 4];
        acc.x += z0.x + z1.x; acc.y += z0.y + z1.y;
        acc.z += z0.z + z1.z; acc.w += z0.w + z1.w;
        e += 2 * S;
    }
    if (e < end) {                 // tail
        int s0 = csr_src[e];
        float4 z0 = *(const float4*)&z[(size_t)s0 * F + f4 * 4];
        acc.x += z0.x; acc.y += z0.y; acc.z += z0.z; acc.w += z0.w;
    }
#pragma unroll
    for (int off = G; off < 64; off <<= 1) {
        acc.x += __shfl_xor(acc.x, off);
        acc.y += __shfl_xor(acc.y, off);
        acc.z += __shfl_xor(acc.z, off);
        acc.w += __shfl_xor(acc.w, off);
    }
    if (slot == 0) {
        const float di = dinv[i];
        float4 zs = *(const float4*)&z[(size_t)i * F + f4 * 4];
        float4 r;
        r.x = di * (acc.x + zs.x); r.y = di * (acc.y + zs.y);
        r.z = di * (acc.z + zs.z); r.w = di * (acc.w + zs.w);
        if (L1MODE) {
            float4 bv = *(const float4*)&bias[f4 * 4];
            r.x = fmaxf(r.x + bv.x, 0.f); r.y = fmaxf(r.y + bv.y, 0.f);
            r.z = fmaxf(r.z + bv.z, 0.f); r.w = fmaxf(r.w + bv.w, 0.f);
        }
        if (PRESCALE_OUT) { r.x *= di; r.y *= di; r.z *= di; r.w *= di; }
        *(float4*)&out[(size_t)i * F + f4 * 4] = r;
    }
}

// --- bf16-input aggregation (prescaled input), fp32 accumulation ------------
template<int F>
__global__ __launch_bounds__(256) void agg_bf16_kernel(
        const unsigned short* __restrict__ z, const int* __restrict__ row_ptr,
        const int* __restrict__ csr_src, const float* __restrict__ dinv,
        float* __restrict__ out, int N) {
    constexpr int G = F / 4;
    constexpr int S = 64 / G;
    const int t = threadIdx.x;
    const int wave = t >> 6;
    const int lane = t & 63;
    const int slot = lane / G;
    const int f4 = lane % G;
    const int i = blockIdx.x * 4 + wave;
    if (i >= N) return;
    const int start = row_ptr[i];
    const int end = row_ptr[i + 1];
    float4 acc = {0.f, 0.f, 0.f, 0.f};
    int e = start + slot;
    while (e + 3 * S < end) {
        int s0 = csr_src[e];
        int s1 = csr_src[e + S];
        int s2 = csr_src[e + 2 * S];
        int s3 = csr_src[e + 3 * S];
        ushort4 u0 = *(const ushort4*)&z[(size_t)s0 * F + f4 * 4];
        ushort4 u1 = *(const ushort4*)&z[(size_t)s1 * F + f4 * 4];
        ushort4 u2 = *(const ushort4*)&z[(size_t)s2 * F + f4 * 4];
        ushort4 u3 = *(const ushort4*)&z[(size_t)s3 * F + f4 * 4];
        acc.x += bf_to_f(u0.x) + bf_to_f(u1.x) + bf_to_f(u2.x) + bf_to_f(u3.x);
        acc.y += bf_to_f(u0.y) + bf_to_f(u1.y) + bf_to_f(u2.y) + bf_to_f(u3.y);
        acc.z += bf_to_f(u0.z) + bf_to_f(u1.z) + bf_to_f(u2.z) + bf_to_f(u3.z);
        acc.w += bf_to_f(u0.w) + bf_to_f(u1.w) + bf_to_f(u2.w) + bf_to_f(u3.w);
        e += 4 * S;
    }
    if (e + S < end) {
        int s0 = csr_src[e];
        int s1 = csr_src[e + S];
        ushort4 u0 = *(const ushort4*)&z[(size_t)s0 * F + f4 * 4];
        ushort4 u1 = *(const ushort4*)&z[(size_t)s1 * F + f4 * 4];
        acc.x += bf_to_f(u0.x) + bf_to_f(u1.x);
        acc.y += bf_to_f(u0.y) + bf_to_f(u1.y);
        acc.z += bf_to_f(u0.z) + bf_to_f(u1.z);
        acc.w += bf_to_f(u0.w) + bf_to_f(u1.w);
        e += 2 * S;
    }
    if (e < end) {
        int s0 = csr_src[e];
        ushort4 u0 = *(const ushort4*)&z[(size_t)s0 * F + f4 * 4];
        acc.x += bf_to_f(u0.x); acc.y += bf_to_f(u0.y);
        acc.z += bf_to_f(u0.z); acc.w += bf_to_f(u0.w);
    }
#pragma unroll
    for (int off = G; off < 64; off <<= 1) {
        acc.x += __shfl_xor(acc.x, off);
        acc.y += __shfl_xor(acc.y, off);
        acc.z += __shfl_xor(acc.z, off);
        acc.w += __shfl_xor(acc.w, off);
    }
    if (slot == 0) {
        const float di = dinv[i];
        ushort4 us = *(const ushort4*)&z[(size_t)i * F + f4 * 4];
        float4 r;
        r.x = di * (acc.x + bf_to_f(us.x));
        r.y = di * (acc.y + bf_to_f(us.y));
        r.z = di * (acc.z + bf_to_f(us.z));
        r.w = di * (acc.w + bf_to_f(us.w));
        *(float4*)&out[(size_t)i * F + f4 * 4] = r;
    }
}

// --- register-tiled GEMM: 64-row x MB-col tile per 256-thread block ---------
// epilogue: optional bias+relu, optional *dinv[row] (prescale for next agg),
// optional bf16 output (RTN).
template<int K, int M, int MB, int RT, bool BIAS_RELU, bool PRESCALE, bool OUTBF16>
__global__ __launch_bounds__(256) void gemm_kernel(
        const float* __restrict__ A, const float* __restrict__ W,
        const float* __restrict__ bias, const float* __restrict__ dinv,
        void* __restrict__ outv, int N) {
    constexpr int CG = MB / 4;
    constexpr int TM = (256 / CG) * RT;
    constexpr int KP = K + 4;            // 2-way bank alias on As reads (free)
    constexpr int MSPLIT = M / MB;
    static_assert(TM == 64, "tile rows");
    __shared__ float As[TM * KP];
    __shared__ float Ws[K * MB];
    __shared__ float bs[MB];
    const int t = threadIdx.x;
    const int base = (blockIdx.x / MSPLIT) * TM;
    const int colb = (blockIdx.x % MSPLIT) * MB;
    const int rows_valid = min(TM, N - base);
    constexpr int KD4 = K / 4;
    for (int idx = t; idx < TM * KD4; idx += 256) {
        int row = idx / KD4, kc = idx % KD4;
        if (row < rows_valid)
            *(float4*)&As[row * KP + kc * 4] = *(const float4*)&A[(size_t)(base + row) * K + kc * 4];
    }
    constexpr int MD4 = MB / 4;
    for (int idx = t; idx < K * MD4; idx += 256) {
        int k = idx / MD4, c4 = idx % MD4;
        *(float4*)&Ws[k * MB + c4 * 4] = *(const float4*)&W[(size_t)k * M + colb + c4 * 4];
    }
    if (BIAS_RELU && t < MB) bs[t] = bias[colb + t];
    __syncthreads();

    const int tc = t % CG;
    const int r0 = (t / CG) * RT;
    const int c0 = tc * 4;
    float4 acc[RT];
#pragma unroll
    for (int r = 0; r < RT; r++) acc[r] = {0.f, 0.f, 0.f, 0.f};

#pragma unroll 4
    for (int k = 0; k < K; k += 4) {
        float4 w0 = *(const float4*)&Ws[(k + 0) * MB + c0];
        float4 w1 = *(const float4*)&Ws[(k + 1) * MB + c0];
        float4 w2 = *(const float4*)&Ws[(k + 2) * MB + c0];
        float4 w3 = *(const float4*)&Ws[(k + 3) * MB + c0];
#pragma unroll
        for (int r = 0; r < RT; r++) {
            float4 av = *(const float4*)&As[(r0 + r) * KP + k];
            acc[r].x += av.x * w0.x + av.y * w1.x + av.z * w2.x + av.w * w3.x;
            acc[r].y += av.x * w0.y + av.y * w1.y + av.z * w2.y + av.w * w3.y;
            acc[r].z += av.x * w0.z + av.y * w1.z + av.z * w2.z + av.w * w3.z;
            acc[r].w += av.x * w0.w + av.y * w1.w + av.z * w2.w + av.w * w3.w;
        }
    }
#pragma unroll
    for (int r = 0; r < RT; r++) {
        int row = base + r0 + r;
        if (row < N) {
            float4 v = acc[r];
            if (BIAS_RELU) {
                float4 bv = *(const float4*)&bs[c0];
                v.x = fmaxf(v.x + bv.x, 0.f); v.y = fmaxf(v.y + bv.y, 0.f);
                v.z = fmaxf(v.z + bv.z, 0.f); v.w = fmaxf(v.w + bv.w, 0.f);
            }
            if (PRESCALE) {
                float d = dinv[row];
                v.x *= d; v.y *= d; v.z *= d; v.w *= d;
            }
            if (OUTBF16) {
                ushort4 u;
                u.x = f_to_bf(v.x); u.y = f_to_bf(v.y);
                u.z = f_to_bf(v.z); u.w = f_to_bf(v.w);
                *(ushort4*)&((unsigned short*)outv)[(size_t)row * M + colb + c0] = u;
            } else {
                *(float4*)&((float*)outv)[(size_t)row * M + colb + c0] = v;
            }
        }
    }
}

// --- final FC: K=32, M=10, tanh --------------------------------------------
__global__ __launch_bounds__(256) void fc2_tanh_kernel(
        const float* __restrict__ A, const float* __restrict__ W,
        const float* __restrict__ bias, float* __restrict__ out, int N) {
    __shared__ float wt[10][36];
    __shared__ float bs[10];
    int t = threadIdx.x;
    for (int idx = t; idx < 320; idx += 256) { int k = idx / 10, m = idx % 10; wt[m][k] = W[idx]; }
    if (t < 10) bs[t] = bias[t];
    __syncthreads();
    int row = blockIdx.x * 256 + t;
    if (row >= N) return;
    float a[32];
    const float4* ap = (const float4*)(A + (size_t)row * 32);
#pragma unroll
    for (int j = 0; j < 8; j++) {
        float4 v = ap[j];
        a[4 * j] = v.x; a[4 * j + 1] = v.y; a[4 * j + 2] = v.z; a[4 * j + 3] = v.w;
    }
#pragma unroll
    for (int m = 0; m < 10; m++) {
        float acc = bs[m];
#pragma unroll
        for (int k = 0; k < 32; k++) acc += a[k] * wt[m][k];
        out[(size_t)row * 10 + m] = tanhf(acc);
    }
}

extern "C" void kernel_launch(void* const* d_in, const int* in_sizes, int n_in,
                              void* d_out, int out_size, void* d_ws, size_t ws_size,
                              hipStream_t stream) {
    const float* x   = (const float*)d_in[0];
    const int*   ei  = (const int*)d_in[1];     // int32 on device
    const float* W1  = (const float*)d_in[2];
    const float* b1  = (const float*)d_in[3];
    const float* W2  = (const float*)d_in[4];
    const float* b2  = (const float*)d_in[5];
    const float* W3  = (const float*)d_in[6];
    const float* b3  = (const float*)d_in[7];
    const float* W4  = (const float*)d_in[8];
    const float* b4  = (const float*)d_in[9];
    const float* Wf1 = (const float*)d_in[10];
    const float* bf1 = (const float*)d_in[11];
    const float* Wf2 = (const float*)d_in[12];
    const float* bf2 = (const float*)d_in[13];

    const int N = in_sizes[0] / 128;   // 100000
    const int E = in_sizes[1] / 2;     // 1600000
    const int* e_src = ei;
    const int* e_dst = ei + E;

    char* p = (char*)d_ws;
    auto carve = [&](size_t bytes) -> void* {
        void* r = (void*)p;
        p += (bytes + 255) & ~(size_t)255;
        return r;
    };
    int*   bucket_cnt = (int*)carve(512 * 4);
    int*   bucket_sta = (int*)carve(512 * 4);
    int*   bucket_cur = (int*)carve(512 * 4);
    float* dinv       = (float*)carve((size_t)N * 4);
    int*   row_ptr    = (int*)carve((size_t)(N + 1) * 4);
    int*   csr_tmp    = (int*)carve((size_t)E * 4);
    int*   csr_src    = (int*)carve((size_t)E * 4);
    float* bufA       = (float*)carve((size_t)N * 128 * 4);
    float* bufB       = (float*)carve((size_t)N * 128 * 4);
    unsigned short* bufC = (unsigned short*)carve((size_t)N * 64 * 2);  // bf16

    const int NB  = (N + 255) / 256;   // 391
    const int AGB = (N + 3) / 4;
    const int GB  = (N + 63) / 64;     // 1563 row-blocks

    // --- graph preprocessing: bucket hist, scan, place, bsort(+dinv) ---
    zero_kernel<<<2, 256, 0, stream>>>(bucket_cnt, 512);
    hist_kernel<<<PREB, 256, 0, stream>>>(e_dst, bucket_cnt, E);
    bucket_scan_kernel<<<1, 512, 0, stream>>>(bucket_cnt, bucket_sta, bucket_cur, E);
    place_kernel<<<PREB, 256, 0, stream>>>(e_src, e_dst, bucket_cur, csr_tmp, E);
    bsort_kernel<<<NBUCK, 256, 0, stream>>>(bucket_sta, csr_tmp, row_ptr, csr_src, dinv, N, E);

    // --- L1 (128->16): prescaled GEMM, then agg(+bias+relu, prescale out) ---
    gemm_kernel<128, 16, 16, 1, false, true, false><<<GB, 256, 0, stream>>>(
        x, W1, nullptr, dinv, bufA, N);
    agg_kernel<16, true, true><<<AGB, 256, 0, stream>>>(
        bufA, row_ptr, csr_src, dinv, b1, bufB, N);

    // --- L2 (16->32): agg (input prescaled), GEMM -> bf16 prescaled z2 ---
    agg_kernel<16, false, false><<<AGB, 256, 0, stream>>>(
        bufB, row_ptr, csr_src, dinv, nullptr, bufA, N);
    gemm_kernel<16, 32, 32, 2, true, true, true><<<GB, 256, 0, stream>>>(
        bufA, W2, b2, dinv, bufC, N);

    // --- L3 (32->64): bf16 agg, GEMM -> bf16 prescaled z3 ---
    agg_bf16_kernel<32><<<AGB, 256, 0, stream>>>(
        bufC, row_ptr, csr_src, dinv, bufA, N);
    gemm_kernel<32, 64, 64, 4, true, true, true><<<GB, 256, 0, stream>>>(
        bufA, W3, b3, dinv, bufC, N);

    // --- L4 (64->128): bf16 agg, M-split GEMM (fp32 out) ---
    agg_bf16_kernel<64><<<AGB, 256, 0, stream>>>(
        bufC, row_ptr, csr_src, dinv, bufA, N);
    gemm_kernel<64, 128, 64, 4, true, false, false><<<GB * 2, 256, 0, stream>>>(
        bufA, W4, b4, nullptr, bufB, N);

    // --- FC head ---
    gemm_kernel<128, 32, 32, 2, true, false, false><<<GB, 256, 0, stream>>>(
        bufB, Wf1, bf1, nullptr, bufA, N);
    fc2_tanh_kernel<<<NB, 256, 0, stream>>>(bufA, Wf2, bf2, (float*)d_out, N);
}

// Round 10
// 410.211 us; speedup vs baseline: 1.4418x; 1.0149x over previous
//
#include <hip/hip_runtime.h>
#include <hip/hip_bf16.h>
#include <cmath>

// ---------------------------------------------------------------------------
// GCN: out = tanh(relu(relu(relu(relu(P(P(P(P(xW1+..)..) .. ))Wf1+bf1)Wf2+bf2
// P = D^-1/2 (A+I) D^-1/2 via CSR (dst-sorted) gather-sum, no float atomics.
// Associativity: aggregate at the *narrower* width of each layer.
// R6: bucketed CSR build. R7: dinv fused into bsort. R8: agg MLP unroll.
// R9: producer-prescaled z (kills per-edge dinv gather) + bf16 transport for
// z2/z3 gathers -> FETCH halved, absmax unchanged (error below floor).
// R10: (a) 16B/lane (ushort8) bf16 gathers: per-edge VALU halves, slot
// parallelism doubles. (b) bf16 transport everywhere downstream of L1:
// agg2/3/4 out, gemm2/3/4 A-in (convert in LDS staging), gemm4 out h4,
// gemmf1 A-in. fp32 accumulation throughout; L1 chain stays fp32.
// ---------------------------------------------------------------------------

#define NBUCK 391              // ceil(100000/256)
#define PREB  391              // ceil(E/4096) edge-phase blocks (16 edges/thread)

typedef __attribute__((ext_vector_type(8))) unsigned short ushort8v;

__device__ __forceinline__ unsigned short f_to_bf(float v) {
    unsigned u = __float_as_uint(v);
    return (unsigned short)((u + 0x7FFF + ((u >> 16) & 1)) >> 16);   // RTN-even
}
__device__ __forceinline__ float bf_to_f(unsigned short v) {
    return __uint_as_float((unsigned)v << 16);
}

__global__ void zero_kernel(int* p, int n) {
    int i = blockIdx.x * 256 + threadIdx.x;
    if (i < n) p[i] = 0;
}

// bucket histogram only (16 edges/thread, LDS-aggregated)
__global__ __launch_bounds__(256) void hist_kernel(
        const int* __restrict__ dst, int* __restrict__ bucket_cnt, int E) {
    __shared__ int bh[NBUCK];
    const int t = threadIdx.x;
    for (int i = t; i < NBUCK; i += 256) bh[i] = 0;
    __syncthreads();
    const int base = blockIdx.x * 4096;
#pragma unroll
    for (int j = 0; j < 16; j++) {
        int e = base + j * 256 + t;
        if (e < E) atomicAdd(&bh[dst[e] >> 8], 1);
    }
    __syncthreads();
    for (int i = t; i < NBUCK; i += 256)
        if (bh[i]) atomicAdd(&bucket_cnt[i], bh[i]);
}

// exclusive scan of bucket_cnt[NBUCK] -> bucket_start (ro) + bucket_cursor (rw)
__global__ void bucket_scan_kernel(const int* __restrict__ bucket_cnt,
                                   int* __restrict__ bucket_start,
                                   int* __restrict__ bucket_cursor, int E) {
    __shared__ int s[512];
    int t = threadIdx.x;
    int v = (t < NBUCK) ? bucket_cnt[t] : 0;
    s[t] = v; __syncthreads();
    for (int off = 1; off < 512; off <<= 1) {
        int x = (t >= off) ? s[t - off] : 0;
        __syncthreads();
        s[t] += x;
        __syncthreads();
    }
    if (t < NBUCK) {
        int excl = s[t] - v;
        bucket_start[t] = excl;
        bucket_cursor[t] = excl;
    }
    if (t == 0) bucket_start[NBUCK] = E;
}

// Phase A: scatter packed edges into bucket-grouped csr_tmp.
// payload = (dst&255)<<17 | src  (src < 2^17). runs per (block,bucket) are
// contiguous -> write frontier 391 lines, L2-resident.
__global__ __launch_bounds__(256) void place_kernel(
        const int* __restrict__ src, const int* __restrict__ dst,
        int* __restrict__ bucket_cursor, int* __restrict__ csr_tmp, int E) {
    __shared__ int hist[NBUCK];
    const int t = threadIdx.x;
    for (int i = t; i < NBUCK; i += 256) hist[i] = 0;
    __syncthreads();
    const int base = blockIdx.x * 4096;
    int pay[16], rb[16];
#pragma unroll
    for (int j = 0; j < 16; j++) {
        int e = base + j * 256 + t;
        if (e < E) {
            int d = dst[e];
            int b = d >> 8;
            int r = atomicAdd(&hist[b], 1);       // r < 4096
            pay[j] = ((d & 255) << 17) | src[e];
            rb[j] = (r << 9) | b;                 // b < 512
        } else rb[j] = -1;
    }
    __syncthreads();
    for (int i = t; i < NBUCK; i += 256) {
        int h = hist[i];
        hist[i] = h ? atomicAdd(&bucket_cursor[i], h) : 0;
    }
    __syncthreads();
#pragma unroll
    for (int j = 0; j < 16; j++) {
        if (rb[j] >= 0) {
            int b = rb[j] & 511;
            int r = rb[j] >> 9;
            csr_tmp[hist[b] + r] = pay[j];
        }
    }
}

// Phase B: one block per bucket -> per-node CSR (row_ptr + csr_src) + dinv.
__global__ __launch_bounds__(256) void bsort_kernel(
        const int* __restrict__ bucket_start, const int* __restrict__ csr_tmp,
        int* __restrict__ row_ptr, int* __restrict__ csr_src,
        float* __restrict__ dinv, int N, int E) {
    __shared__ int c[256], s[256], cur[256];
    const int b = blockIdx.x;
    const int t = threadIdx.x;
    const int start = bucket_start[b];
    const int end = bucket_start[b + 1];
    c[t] = 0;
    __syncthreads();
    for (int e = start + t; e < end; e += 256)
        atomicAdd(&c[csr_tmp[e] >> 17], 1);
    __syncthreads();
    int v = c[t];
    s[t] = v; __syncthreads();
    for (int off = 1; off < 256; off <<= 1) {
        int x = (t >= off) ? s[t - off] : 0;
        __syncthreads();
        s[t] += x;
        __syncthreads();
    }
    int excl = s[t] - v;
    int node = (b << 8) + t;
    if (node < N) {
        row_ptr[node] = start + excl;
        dinv[node] = rsqrtf((float)v + 1.0f);
    }
    cur[t] = start + excl;
    if (b == NBUCK - 1 && t == 0) row_ptr[N] = E;
    __syncthreads();
    for (int e = start + t; e < end; e += 256) {
        int p = csr_tmp[e];
        int pos = atomicAdd(&cur[p >> 17], 1);
        csr_src[pos] = p & 0x1FFFF;
    }
}

// --- fp32-input aggregation over PRESCALED input zs = dinv*z ----------------
// out[i] = dinv[i]*(sum_e zs[src_e] + zs[i]); optional bias+relu (L1MODE),
// optional output prescale, optional bf16 output.
template<int F, bool L1MODE, bool PRESCALE_OUT, bool OUTBF>
__global__ __launch_bounds__(256) void agg_f32_kernel(
        const float* __restrict__ z, const int* __restrict__ row_ptr,
        const int* __restrict__ csr_src, const float* __restrict__ dinv,
        const float* __restrict__ bias, void* __restrict__ outv, int N) {
    constexpr int G = F / 4;       // lanes per row (16B each)
    constexpr int S = 64 / G;      // edge slots per wave
    const int t = threadIdx.x;
    const int wave = t >> 6;
    const int lane = t & 63;
    const int slot = lane / G;
    const int f4 = lane % G;
    const int i = blockIdx.x * 4 + wave;
    if (i >= N) return;            // wave-uniform exit
    const int start = row_ptr[i];
    const int end = row_ptr[i + 1];
    float4 acc = {0.f, 0.f, 0.f, 0.f};
    int e = start + slot;
    while (e + 3 * S < end) {      // U=4: 4 independent chains per slot
        int s0 = csr_src[e];
        int s1 = csr_src[e + S];
        int s2 = csr_src[e + 2 * S];
        int s3 = csr_src[e + 3 * S];
        float4 z0 = *(const float4*)&z[(size_t)s0 * F + f4 * 4];
        float4 z1 = *(const float4*)&z[(size_t)s1 * F + f4 * 4];
        float4 z2 = *(const float4*)&z[(size_t)s2 * F + f4 * 4];
        float4 z3 = *(const float4*)&z[(size_t)s3 * F + f4 * 4];
        acc.x += z0.x + z1.x + z2.x + z3.x;
        acc.y += z0.y + z1.y + z2.y + z3.y;
        acc.z += z0.z + z1.z + z2.z + z3.z;
        acc.w += z0.w + z1.w + z2.w + z3.w;
        e += 4 * S;
    }
    if (e + S < end) {             // U=2
        int s0 = csr_src[e];
        int s1 = csr_src[e + S];
        float4 z0 = *(const float4*)&z[(size_t)s0 * F + f4 * 4];
        float4 z1 = *(const float4*)&z[(size_t)s1 * F + f4 * 4];
        acc.x += z0.x + z1.x; acc.y += z0.y + z1.y;
        acc.z += z0.z + z1.z; acc.w += z0.w + z1.w;
        e += 2 * S;
    }
    if (e < end) {                 // tail
        int s0 = csr_src[e];
        float4 z0 = *(const float4*)&z[(size_t)s0 * F + f4 * 4];
        acc.x += z0.x; acc.y += z0.y; acc.z += z0.z; acc.w += z0.w;
    }
#pragma unroll
    for (int off = G; off < 64; off <<= 1) {
        acc.x += __shfl_xor(acc.x, off);
        acc.y += __shfl_xor(acc.y, off);
        acc.z += __shfl_xor(acc.z, off);
        acc.w += __shfl_xor(acc.w, off);
    }
    if (slot == 0) {
        const float di = dinv[i];
        float4 zs = *(const float4*)&z[(size_t)i * F + f4 * 4];
        float4 r;
        r.x = di * (acc.x + zs.x); r.y = di * (acc.y + zs.y);
        r.z = di * (acc.z + zs.z); r.w = di * (acc.w + zs.w);
        if (L1MODE) {
            float4 bv = *(const float4*)&bias[f4 * 4];
            r.x = fmaxf(r.x + bv.x, 0.f); r.y = fmaxf(r.y + bv.y, 0.f);
            r.z = fmaxf(r.z + bv.z, 0.f); r.w = fmaxf(r.w + bv.w, 0.f);
        }
        if (PRESCALE_OUT) { r.x *= di; r.y *= di; r.z *= di; r.w *= di; }
        if (OUTBF) {
            ushort4 u;
            u.x = f_to_bf(r.x); u.y = f_to_bf(r.y);
            u.z = f_to_bf(r.z); u.w = f_to_bf(r.w);
            *(ushort4*)&((unsigned short*)outv)[(size_t)i * F + f4 * 4] = u;
        } else {
            *(float4*)&((float*)outv)[(size_t)i * F + f4 * 4] = r;
        }
    }
}

// --- bf16-input aggregation, 16B/lane (ushort8) loads, fp32 accum, bf16 out -
template<int F>
__global__ __launch_bounds__(256) void agg_bf_kernel(
        const unsigned short* __restrict__ z, const int* __restrict__ row_ptr,
        const int* __restrict__ csr_src, const float* __restrict__ dinv,
        unsigned short* __restrict__ out, int N) {
    constexpr int G = F / 8;       // lanes per row (16B of bf16 each)
    constexpr int S = 64 / G;      // edge slots per wave
    const int t = threadIdx.x;
    const int wave = t >> 6;
    const int lane = t & 63;
    const int slot = lane / G;
    const int c0 = (lane % G) * 8; // bf16 element offset within row
    const int i = blockIdx.x * 4 + wave;
    if (i >= N) return;
    const int start = row_ptr[i];
    const int end = row_ptr[i + 1];
    float acc[8] = {0.f, 0.f, 0.f, 0.f, 0.f, 0.f, 0.f, 0.f};
    int e = start + slot;
    while (e + 3 * S < end) {
        int s0 = csr_src[e];
        int s1 = csr_src[e + S];
        int s2 = csr_src[e + 2 * S];
        int s3 = csr_src[e + 3 * S];
        ushort8v u0 = *(const ushort8v*)&z[(size_t)s0 * F + c0];
        ushort8v u1 = *(const ushort8v*)&z[(size_t)s1 * F + c0];
        ushort8v u2 = *(const ushort8v*)&z[(size_t)s2 * F + c0];
        ushort8v u3 = *(const ushort8v*)&z[(size_t)s3 * F + c0];
#pragma unroll
        for (int j = 0; j < 8; j++)
            acc[j] += (bf_to_f(u0[j]) + bf_to_f(u1[j])) + (bf_to_f(u2[j]) + bf_to_f(u3[j]));
        e += 4 * S;
    }
    if (e + S < end) {
        int s0 = csr_src[e];
        int s1 = csr_src[e + S];
        ushort8v u0 = *(const ushort8v*)&z[(size_t)s0 * F + c0];
        ushort8v u1 = *(const ushort8v*)&z[(size_t)s1 * F + c0];
#pragma unroll
        for (int j = 0; j < 8; j++) acc[j] += bf_to_f(u0[j]) + bf_to_f(u1[j]);
        e += 2 * S;
    }
    if (e < end) {
        int s0 = csr_src[e];
        ushort8v u0 = *(const ushort8v*)&z[(size_t)s0 * F + c0];
#pragma unroll
        for (int j = 0; j < 8; j++) acc[j] += bf_to_f(u0[j]);
    }
#pragma unroll
    for (int off = G; off < 64; off <<= 1) {
#pragma unroll
        for (int j = 0; j < 8; j++) acc[j] += __shfl_xor(acc[j], off);
    }
    if (slot == 0) {
        const float di = dinv[i];
        ushort8v us = *(const ushort8v*)&z[(size_t)i * F + c0];
        ushort8v uo;
#pragma unroll
        for (int j = 0; j < 8; j++) uo[j] = f_to_bf(di * (acc[j] + bf_to_f(us[j])));
        *(ushort8v*)&out[(size_t)i * F + c0] = uo;
    }
}

// --- register-tiled GEMM: 64-row x MB-col tile per 256-thread block ---------
// A input fp32 or bf16 (converted to fp32 in LDS staging); epilogue:
// optional bias+relu, *dinv[row] prescale, bf16 output.
template<int K, int M, int MB, int RT, bool BIAS_RELU, bool PRESCALE, bool INBF, bool OUTBF>
__global__ __launch_bounds__(256) void gemm_kernel(
        const void* __restrict__ Av, const float* __restrict__ W,
        const float* __restrict__ bias, const float* __restrict__ dinv,
        void* __restrict__ outv, int N) {
    constexpr int CG = MB / 4;
    constexpr int TM = (256 / CG) * RT;
    constexpr int KP = K + 4;            // 2-way bank alias on As reads (free)
    constexpr int MSPLIT = M / MB;
    static_assert(TM == 64, "tile rows");
    __shared__ float As[TM * KP];
    __shared__ float Ws[K * MB];
    __shared__ float bs[MB];
    const int t = threadIdx.x;
    const int base = (blockIdx.x / MSPLIT) * TM;
    const int colb = (blockIdx.x % MSPLIT) * MB;
    const int rows_valid = min(TM, N - base);
    if (INBF) {
        constexpr int KD8 = K / 8;
        const unsigned short* A = (const unsigned short*)Av;
        for (int idx = t; idx < TM * KD8; idx += 256) {
            int row = idx / KD8, kc = idx % KD8;
            if (row < rows_valid) {
                ushort8v u = *(const ushort8v*)&A[(size_t)(base + row) * K + kc * 8];
                float4 lo = {bf_to_f(u[0]), bf_to_f(u[1]), bf_to_f(u[2]), bf_to_f(u[3])};
                float4 hi = {bf_to_f(u[4]), bf_to_f(u[5]), bf_to_f(u[6]), bf_to_f(u[7])};
                *(float4*)&As[row * KP + kc * 8] = lo;
                *(float4*)&As[row * KP + kc * 8 + 4] = hi;
            }
        }
    } else {
        constexpr int KD4 = K / 4;
        const float* A = (const float*)Av;
        for (int idx = t; idx < TM * KD4; idx += 256) {
            int row = idx / KD4, kc = idx % KD4;
            if (row < rows_valid)
                *(float4*)&As[row * KP + kc * 4] = *(const float4*)&A[(size_t)(base + row) * K + kc * 4];
        }
    }
    constexpr int MD4 = MB / 4;
    for (int idx = t; idx < K * MD4; idx += 256) {
        int k = idx / MD4, c4 = idx % MD4;
        *(float4*)&Ws[k * MB + c4 * 4] = *(const float4*)&W[(size_t)k * M + colb + c4 * 4];
    }
    if (BIAS_RELU && t < MB) bs[t] = bias[colb + t];
    __syncthreads();

    const int tc = t % CG;
    const int r0 = (t / CG) * RT;
    const int c0 = tc * 4;
    float4 acc[RT];
#pragma unroll
    for (int r = 0; r < RT; r++) acc[r] = {0.f, 0.f, 0.f, 0.f};

#pragma unroll 4
    for (int k = 0; k < K; k += 4) {
        float4 w0 = *(const float4*)&Ws[(k + 0) * MB + c0];
        float4 w1 = *(const float4*)&Ws[(k + 1) * MB + c0];
        float4 w2 = *(const float4*)&Ws[(k + 2) * MB + c0];
        float4 w3 = *(const float4*)&Ws[(k + 3) * MB + c0];
#pragma unroll
        for (int r = 0; r < RT; r++) {
            float4 av = *(const float4*)&As[(r0 + r) * KP + k];
            acc[r].x += av.x * w0.x + av.y * w1.x + av.z * w2.x + av.w * w3.x;
            acc[r].y += av.x * w0.y + av.y * w1.y + av.z * w2.y + av.w * w3.y;
            acc[r].z += av.x * w0.z + av.y * w1.z + av.z * w2.z + av.w * w3.z;
            acc[r].w += av.x * w0.w + av.y * w1.w + av.z * w2.w + av.w * w3.w;
        }
    }
#pragma unroll
    for (int r = 0; r < RT; r++) {
        int row = base + r0 + r;
        if (row < N) {
            float4 v = acc[r];
            if (BIAS_RELU) {
                float4 bv = *(const float4*)&bs[c0];
                v.x = fmaxf(v.x + bv.x, 0.f); v.y = fmaxf(v.y + bv.y, 0.f);
                v.z = fmaxf(v.z + bv.z, 0.f); v.w = fmaxf(v.w + bv.w, 0.f);
            }
            if (PRESCALE) {
                float d = dinv[row];
                v.x *= d; v.y *= d; v.z *= d; v.w *= d;
            }
            if (OUTBF) {
                ushort4 u;
                u.x = f_to_bf(v.x); u.y = f_to_bf(v.y);
                u.z = f_to_bf(v.z); u.w = f_to_bf(v.w);
                *(ushort4*)&((unsigned short*)outv)[(size_t)row * M + colb + c0] = u;
            } else {
                *(float4*)&((float*)outv)[(size_t)row * M + colb + c0] = v;
            }
        }
    }
}

// --- final FC: K=32, M=10, tanh --------------------------------------------
__global__ __launch_bounds__(256) void fc2_tanh_kernel(
        const float* __restrict__ A, const float* __restrict__ W,
        const float* __restrict__ bias, float* __restrict__ out, int N) {
    __shared__ float wt[10][36];
    __shared__ float bs[10];
    int t = threadIdx.x;
    for (int idx = t; idx < 320; idx += 256) { int k = idx / 10, m = idx % 10; wt[m][k] = W[idx]; }
    if (t < 10) bs[t] = bias[t];
    __syncthreads();
    int row = blockIdx.x * 256 + t;
    if (row >= N) return;
    float a[32];
    const float4* ap = (const float4*)(A + (size_t)row * 32);
#pragma unroll
    for (int j = 0; j < 8; j++) {
        float4 v = ap[j];
        a[4 * j] = v.x; a[4 * j + 1] = v.y; a[4 * j + 2] = v.z; a[4 * j + 3] = v.w;
    }
#pragma unroll
    for (int m = 0; m < 10; m++) {
        float acc = bs[m];
#pragma unroll
        for (int k = 0; k < 32; k++) acc += a[k] * wt[m][k];
        out[(size_t)row * 10 + m] = tanhf(acc);
    }
}

extern "C" void kernel_launch(void* const* d_in, const int* in_sizes, int n_in,
                              void* d_out, int out_size, void* d_ws, size_t ws_size,
                              hipStream_t stream) {
    const float* x   = (const float*)d_in[0];
    const int*   ei  = (const int*)d_in[1];     // int32 on device
    const float* W1  = (const float*)d_in[2];
    const float* b1  = (const float*)d_in[3];
    const float* W2  = (const float*)d_in[4];
    const float* b2  = (const float*)d_in[5];
    const float* W3  = (const float*)d_in[6];
    const float* b3  = (const float*)d_in[7];
    const float* W4  = (const float*)d_in[8];
    const float* b4  = (const float*)d_in[9];
    const float* Wf1 = (const float*)d_in[10];
    const float* bf1 = (const float*)d_in[11];
    const float* Wf2 = (const float*)d_in[12];
    const float* bf2 = (const float*)d_in[13];

    const int N = in_sizes[0] / 128;   // 100000
    const int E = in_sizes[1] / 2;     // 1600000
    const int* e_src = ei;
    const int* e_dst = ei + E;

    char* p = (char*)d_ws;
    auto carve = [&](size_t bytes) -> void* {
        void* r = (void*)p;
        p += (bytes + 255) & ~(size_t)255;
        return r;
    };
    int*   bucket_cnt = (int*)carve(512 * 4);
    int*   bucket_sta = (int*)carve(512 * 4);
    int*   bucket_cur = (int*)carve(512 * 4);
    float* dinv       = (float*)carve((size_t)N * 4);
    int*   row_ptr    = (int*)carve((size_t)(N + 1) * 4);
    int*   csr_tmp    = (int*)carve((size_t)E * 4);
    int*   csr_src    = (int*)carve((size_t)E * 4);
    float* bufA       = (float*)carve((size_t)N * 32 * 4);        // z1 / h5 fp32
    float* bufB       = (float*)carve((size_t)N * 16 * 4);        // z1' fp32
    unsigned short* bufP = (unsigned short*)carve((size_t)N * 128 * 2); // bf16 ping
    unsigned short* bufQ = (unsigned short*)carve((size_t)N * 128 * 2); // bf16 pong

    const int NB  = (N + 255) / 256;   // 391
    const int AGB = (N + 3) / 4;
    const int GB  = (N + 63) / 64;     // 1563 row-blocks

    // --- graph preprocessing: bucket hist, scan, place, bsort(+dinv) ---
    zero_kernel<<<2, 256, 0, stream>>>(bucket_cnt, 512);
    hist_kernel<<<PREB, 256, 0, stream>>>(e_dst, bucket_cnt, E);
    bucket_scan_kernel<<<1, 512, 0, stream>>>(bucket_cnt, bucket_sta, bucket_cur, E);
    place_kernel<<<PREB, 256, 0, stream>>>(e_src, e_dst, bucket_cur, csr_tmp, E);
    bsort_kernel<<<NBUCK, 256, 0, stream>>>(bucket_sta, csr_tmp, row_ptr, csr_src, dinv, N, E);

    // --- L1 (128->16): prescaled GEMM (fp32), agg1 (bias+relu, prescale) ---
    gemm_kernel<128, 16, 16, 1, false, true, false, false><<<GB, 256, 0, stream>>>(
        x, W1, nullptr, dinv, bufA, N);
    agg_f32_kernel<16, true, true, false><<<AGB, 256, 0, stream>>>(
        bufA, row_ptr, csr_src, dinv, b1, bufB, N);

    // --- L2 (16->32): agg2 fp32->bf16, GEMM bf16->bf16 prescaled z2 ---
    agg_f32_kernel<16, false, false, true><<<AGB, 256, 0, stream>>>(
        bufB, row_ptr, csr_src, dinv, nullptr, bufP, N);
    gemm_kernel<16, 32, 32, 2, true, true, true, true><<<GB, 256, 0, stream>>>(
        bufP, W2, b2, dinv, bufQ, N);

    // --- L3 (32->64): bf16 agg, GEMM bf16->bf16 prescaled z3 ---
    agg_bf_kernel<32><<<AGB, 256, 0, stream>>>(
        bufQ, row_ptr, csr_src, dinv, bufP, N);
    gemm_kernel<32, 64, 64, 4, true, true, true, true><<<GB, 256, 0, stream>>>(
        bufP, W3, b3, dinv, bufQ, N);

    // --- L4 (64->128): bf16 agg, M-split GEMM bf16->bf16 h4 ---
    agg_bf_kernel<64><<<AGB, 256, 0, stream>>>(
        bufQ, row_ptr, csr_src, dinv, bufP, N);
    gemm_kernel<64, 128, 64, 4, true, false, true, true><<<GB * 2, 256, 0, stream>>>(
        bufP, W4, b4, nullptr, bufQ, N);

    // --- FC head: gemmf1 bf16->fp32, fc2 tanh ---
    gemm_kernel<128, 32, 32, 2, true, false, true, false><<<GB, 256, 0, stream>>>(
        bufQ, Wf1, bf1, nullptr, bufA, N);
    fc2_tanh_kernel<<<NB, 256, 0, stream>>>(bufA, Wf2, bf2, (float*)d_out, N);
}

// Round 12
// 402.607 us; speedup vs baseline: 1.4691x; 1.0189x over previous
//
#include <hip/hip_runtime.h>
#include <hip/hip_bf16.h>
#include <cmath>

// ---------------------------------------------------------------------------
// GCN: out = tanh(relu(relu(relu(relu(P(P(P(P(xW1+..)..) .. ))Wf1+bf1)Wf2+bf2
// P = D^-1/2 (A+I) D^-1/2 via CSR (dst-sorted) gather-sum, no float atomics.
// Associativity: aggregate at the *narrower* width of each layer.
// R6: bucketed CSR build. R7: dinv fused into bsort. R8: agg MLP unroll x4.
// R9/R10: producer-prescaled z + bf16 transport for z2/z3 -> FETCH halved.
// R11: full-bf16 transport (16-wide streams = 3.2MB -> per-XCD L2-fit) +
// fused FC head. FAILED: wt2 staging used `if (t<320)` with 256 threads ->
// Wf2 k>=25 never loaded. R12: restore strided staging loop (1-line fix).
// ---------------------------------------------------------------------------

#define NBUCK 391              // ceil(100000/256)
#define PREB  391              // ceil(E/4096) edge-phase blocks (16 edges/thread)

typedef __attribute__((ext_vector_type(8))) unsigned short ushort8v;

__device__ __forceinline__ unsigned short f_to_bf(float v) {
    unsigned u = __float_as_uint(v);
    return (unsigned short)((u + 0x7FFF + ((u >> 16) & 1)) >> 16);   // RTN-even
}
__device__ __forceinline__ float bf_to_f(unsigned short v) {
    return __uint_as_float((unsigned)v << 16);
}

template<int VE> struct BFV;
template<> struct BFV<4> {
    using T = ushort4;
    __device__ static inline void unpack(const T& u, float* f) {
        f[0] = bf_to_f(u.x); f[1] = bf_to_f(u.y);
        f[2] = bf_to_f(u.z); f[3] = bf_to_f(u.w);
    }
    __device__ static inline T pack(const float* f) {
        T u; u.x = f_to_bf(f[0]); u.y = f_to_bf(f[1]);
        u.z = f_to_bf(f[2]); u.w = f_to_bf(f[3]); return u;
    }
};
template<> struct BFV<8> {
    using T = ushort8v;
    __device__ static inline void unpack(const T& u, float* f) {
#pragma unroll
        for (int j = 0; j < 8; j++) f[j] = bf_to_f(u[j]);
    }
    __device__ static inline T pack(const float* f) {
        T u;
#pragma unroll
        for (int j = 0; j < 8; j++) u[j] = f_to_bf(f[j]);
        return u;
    }
};

__global__ void zero_kernel(int* p, int n) {
    int i = blockIdx.x * 256 + threadIdx.x;
    if (i < n) p[i] = 0;
}

// bucket histogram only (16 edges/thread, LDS-aggregated)
__global__ __launch_bounds__(256) void hist_kernel(
        const int* __restrict__ dst, int* __restrict__ bucket_cnt, int E) {
    __shared__ int bh[NBUCK];
    const int t = threadIdx.x;
    for (int i = t; i < NBUCK; i += 256) bh[i] = 0;
    __syncthreads();
    const int base = blockIdx.x * 4096;
#pragma unroll
    for (int j = 0; j < 16; j++) {
        int e = base + j * 256 + t;
        if (e < E) atomicAdd(&bh[dst[e] >> 8], 1);
    }
    __syncthreads();
    for (int i = t; i < NBUCK; i += 256)
        if (bh[i]) atomicAdd(&bucket_cnt[i], bh[i]);
}

// exclusive scan of bucket_cnt[NBUCK] -> bucket_start (ro) + bucket_cursor (rw)
__global__ void bucket_scan_kernel(const int* __restrict__ bucket_cnt,
                                   int* __restrict__ bucket_start,
                                   int* __restrict__ bucket_cursor, int E) {
    __shared__ int s[512];
    int t = threadIdx.x;
    int v = (t < NBUCK) ? bucket_cnt[t] : 0;
    s[t] = v; __syncthreads();
    for (int off = 1; off < 512; off <<= 1) {
        int x = (t >= off) ? s[t - off] : 0;
        __syncthreads();
        s[t] += x;
        __syncthreads();
    }
    if (t < NBUCK) {
        int excl = s[t] - v;
        bucket_start[t] = excl;
        bucket_cursor[t] = excl;
    }
    if (t == 0) bucket_start[NBUCK] = E;
}

// Phase A: scatter packed edges into bucket-grouped csr_tmp.
// payload = (dst&255)<<17 | src. write frontier = 391 lines (L2-resident).
__global__ __launch_bounds__(256) void place_kernel(
        const int* __restrict__ src, const int* __restrict__ dst,
        int* __restrict__ bucket_cursor, int* __restrict__ csr_tmp, int E) {
    __shared__ int hist[NBUCK];
    const int t = threadIdx.x;
    for (int i = t; i < NBUCK; i += 256) hist[i] = 0;
    __syncthreads();
    const int base = blockIdx.x * 4096;
    int pay[16], rb[16];
#pragma unroll
    for (int j = 0; j < 16; j++) {
        int e = base + j * 256 + t;
        if (e < E) {
            int d = dst[e];
            int b = d >> 8;
            int r = atomicAdd(&hist[b], 1);       // r < 4096
            pay[j] = ((d & 255) << 17) | src[e];
            rb[j] = (r << 9) | b;                 // b < 512
        } else rb[j] = -1;
    }
    __syncthreads();
    for (int i = t; i < NBUCK; i += 256) {
        int h = hist[i];
        hist[i] = h ? atomicAdd(&bucket_cursor[i], h) : 0;
    }
    __syncthreads();
#pragma unroll
    for (int j = 0; j < 16; j++) {
        if (rb[j] >= 0) {
            int b = rb[j] & 511;
            int r = rb[j] >> 9;
            csr_tmp[hist[b] + r] = pay[j];
        }
    }
}

// Phase B: one block per bucket -> per-node CSR (row_ptr + csr_src) + dinv.
__global__ __launch_bounds__(256) void bsort_kernel(
        const int* __restrict__ bucket_start, const int* __restrict__ csr_tmp,
        int* __restrict__ row_ptr, int* __restrict__ csr_src,
        float* __restrict__ dinv, int N, int E) {
    __shared__ int c[256], s[256], cur[256];
    const int b = blockIdx.x;
    const int t = threadIdx.x;
    const int start = bucket_start[b];
    const int end = bucket_start[b + 1];
    c[t] = 0;
    __syncthreads();
    for (int e = start + t; e < end; e += 256)
        atomicAdd(&c[csr_tmp[e] >> 17], 1);
    __syncthreads();
    int v = c[t];
    s[t] = v; __syncthreads();
    for (int off = 1; off < 256; off <<= 1) {
        int x = (t >= off) ? s[t - off] : 0;
        __syncthreads();
        s[t] += x;
        __syncthreads();
    }
    int excl = s[t] - v;
    int node = (b << 8) + t;
    if (node < N) {
        row_ptr[node] = start + excl;
        dinv[node] = rsqrtf((float)v + 1.0f);
    }
    cur[t] = start + excl;
    if (b == NBUCK - 1 && t == 0) row_ptr[N] = E;
    __syncthreads();
    for (int e = start + t; e < end; e += 256) {
        int p = csr_tmp[e];
        int pos = atomicAdd(&cur[p >> 17], 1);
        csr_src[pos] = p & 0x1FFFF;
    }
}

// --- bf16 aggregation over PRESCALED input zs = dinv*z, bf16 out ------------
// out[i] = dinv[i]*(sum_e zs[src_e] + zs[i]); optional bias+relu (L1MODE),
// optional output prescale. VE = bf16 elems/lane (4 or 8); G=F/VE lanes/row.
template<int F, int VE, bool L1MODE, bool PRESCALE_OUT>
__global__ __launch_bounds__(256) void agg_bf_kernel(
        const unsigned short* __restrict__ z, const int* __restrict__ row_ptr,
        const int* __restrict__ csr_src, const float* __restrict__ dinv,
        const float* __restrict__ bias, unsigned short* __restrict__ out, int N) {
    using VT = typename BFV<VE>::T;
    constexpr int G = F / VE;      // lanes per row
    constexpr int S = 64 / G;      // edge slots per wave
    const int t = threadIdx.x;
    const int wave = t >> 6;
    const int lane = t & 63;
    const int slot = lane / G;
    const int c0 = (lane % G) * VE;
    const int i = blockIdx.x * 4 + wave;
    if (i >= N) return;            // wave-uniform exit
    const int start = row_ptr[i];
    const int end = row_ptr[i + 1];
    float acc[VE];
#pragma unroll
    for (int j = 0; j < VE; j++) acc[j] = 0.f;
    int e = start + slot;
    while (e + 3 * S < end) {      // U=4: 4 independent chains per slot
        int s0 = csr_src[e];
        int s1 = csr_src[e + S];
        int s2 = csr_src[e + 2 * S];
        int s3 = csr_src[e + 3 * S];
        VT u0 = *(const VT*)&z[(size_t)s0 * F + c0];
        VT u1 = *(const VT*)&z[(size_t)s1 * F + c0];
        VT u2 = *(const VT*)&z[(size_t)s2 * F + c0];
        VT u3 = *(const VT*)&z[(size_t)s3 * F + c0];
        float f0[VE], f1[VE], f2[VE], f3[VE];
        BFV<VE>::unpack(u0, f0); BFV<VE>::unpack(u1, f1);
        BFV<VE>::unpack(u2, f2); BFV<VE>::unpack(u3, f3);
#pragma unroll
        for (int j = 0; j < VE; j++) acc[j] += (f0[j] + f1[j]) + (f2[j] + f3[j]);
        e += 4 * S;
    }
    if (e + S < end) {             // U=2
        int s0 = csr_src[e];
        int s1 = csr_src[e + S];
        VT u0 = *(const VT*)&z[(size_t)s0 * F + c0];
        VT u1 = *(const VT*)&z[(size_t)s1 * F + c0];
        float f0[VE], f1[VE];
        BFV<VE>::unpack(u0, f0); BFV<VE>::unpack(u1, f1);
#pragma unroll
        for (int j = 0; j < VE; j++) acc[j] += f0[j] + f1[j];
        e += 2 * S;
    }
    if (e < end) {                 // tail
        int s0 = csr_src[e];
        VT u0 = *(const VT*)&z[(size_t)s0 * F + c0];
        float f0[VE];
        BFV<VE>::unpack(u0, f0);
#pragma unroll
        for (int j = 0; j < VE; j++) acc[j] += f0[j];
    }
#pragma unroll
    for (int off = G; off < 64; off <<= 1) {
#pragma unroll
        for (int j = 0; j < VE; j++) acc[j] += __shfl_xor(acc[j], off);
    }
    if (slot == 0) {
        const float di = dinv[i];
        VT us = *(const VT*)&z[(size_t)i * F + c0];
        float fs[VE], r[VE];
        BFV<VE>::unpack(us, fs);
#pragma unroll
        for (int j = 0; j < VE; j++) r[j] = di * (acc[j] + fs[j]);
        if (L1MODE) {
#pragma unroll
            for (int j = 0; j < VE; j++) r[j] = fmaxf(r[j] + bias[c0 + j], 0.f);
        }
        if (PRESCALE_OUT) {
#pragma unroll
            for (int j = 0; j < VE; j++) r[j] *= di;
        }
        *(VT*)&out[(size_t)i * F + c0] = BFV<VE>::pack(r);
    }
}

// --- register-tiled GEMM: 64-row x MB-col tile per 256-thread block ---------
// A input fp32 or bf16 (converted to fp32 in LDS staging); epilogue:
// optional bias+relu, *dinv[row] prescale, bf16 output.
template<int K, int M, int MB, int RT, bool BIAS_RELU, bool PRESCALE, bool INBF, bool OUTBF>
__global__ __launch_bounds__(256) void gemm_kernel(
        const void* __restrict__ Av, const float* __restrict__ W,
        const float* __restrict__ bias, const float* __restrict__ dinv,
        void* __restrict__ outv, int N) {
    constexpr int CG = MB / 4;
    constexpr int TM = (256 / CG) * RT;
    constexpr int KP = K + 4;            // 2-way bank alias on As reads (free)
    constexpr int MSPLIT = M / MB;
    static_assert(TM == 64, "tile rows");
    __shared__ float As[TM * KP];
    __shared__ float Ws[K * MB];
    __shared__ float bs[MB];
    const int t = threadIdx.x;
    const int base = (blockIdx.x / MSPLIT) * TM;
    const int colb = (blockIdx.x % MSPLIT) * MB;
    const int rows_valid = min(TM, N - base);
    if (INBF) {
        constexpr int KD8 = K / 8;
        const unsigned short* A = (const unsigned short*)Av;
        for (int idx = t; idx < TM * KD8; idx += 256) {
            int row = idx / KD8, kc = idx % KD8;
            if (row < rows_valid) {
                ushort8v u = *(const ushort8v*)&A[(size_t)(base + row) * K + kc * 8];
                float4 lo = {bf_to_f(u[0]), bf_to_f(u[1]), bf_to_f(u[2]), bf_to_f(u[3])};
                float4 hi = {bf_to_f(u[4]), bf_to_f(u[5]), bf_to_f(u[6]), bf_to_f(u[7])};
                *(float4*)&As[row * KP + kc * 8] = lo;
                *(float4*)&As[row * KP + kc * 8 + 4] = hi;
            }
        }
    } else {
        constexpr int KD4 = K / 4;
        const float* A = (const float*)Av;
        for (int idx = t; idx < TM * KD4; idx += 256) {
            int row = idx / KD4, kc = idx % KD4;
            if (row < rows_valid)
                *(float4*)&As[row * KP + kc * 4] = *(const float4*)&A[(size_t)(base + row) * K + kc * 4];
        }
    }
    constexpr int MD4 = MB / 4;
    for (int idx = t; idx < K * MD4; idx += 256) {
        int k = idx / MD4, c4 = idx % MD4;
        *(float4*)&Ws[k * MB + c4 * 4] = *(const float4*)&W[(size_t)k * M + colb + c4 * 4];
    }
    if (BIAS_RELU && t < MB) bs[t] = bias[colb + t];
    __syncthreads();

    const int tc = t % CG;
    const int r0 = (t / CG) * RT;
    const int c0 = tc * 4;
    float4 acc[RT];
#pragma unroll
    for (int r = 0; r < RT; r++) acc[r] = {0.f, 0.f, 0.f, 0.f};

#pragma unroll 4
    for (int k = 0; k < K; k += 4) {
        float4 w0 = *(const float4*)&Ws[(k + 0) * MB + c0];
        float4 w1 = *(const float4*)&Ws[(k + 1) * MB + c0];
        float4 w2 = *(const float4*)&Ws[(k + 2) * MB + c0];
        float4 w3 = *(const float4*)&Ws[(k + 3) * MB + c0];
#pragma unroll
        for (int r = 0; r < RT; r++) {
            float4 av = *(const float4*)&As[(r0 + r) * KP + k];
            acc[r].x += av.x * w0.x + av.y * w1.x + av.z * w2.x + av.w * w3.x;
            acc[r].y += av.x * w0.y + av.y * w1.y + av.z * w2.y + av.w * w3.y;
            acc[r].z += av.x * w0.z + av.y * w1.z + av.z * w2.z + av.w * w3.z;
            acc[r].w += av.x * w0.w + av.y * w1.w + av.z * w2.w + av.w * w3.w;
        }
    }
#pragma unroll
    for (int r = 0; r < RT; r++) {
        int row = base + r0 + r;
        if (row < N) {
            float4 v = acc[r];
            if (BIAS_RELU) {
                float4 bv = *(const float4*)&bs[c0];
                v.x = fmaxf(v.x + bv.x, 0.f); v.y = fmaxf(v.y + bv.y, 0.f);
                v.z = fmaxf(v.z + bv.z, 0.f); v.w = fmaxf(v.w + bv.w, 0.f);
            }
            if (PRESCALE) {
                float d = dinv[row];
                v.x *= d; v.y *= d; v.z *= d; v.w *= d;
            }
            if (OUTBF) {
                ushort4 u;
                u.x = f_to_bf(v.x); u.y = f_to_bf(v.y);
                u.z = f_to_bf(v.z); u.w = f_to_bf(v.w);
                *(ushort4*)&((unsigned short*)outv)[(size_t)row * M + colb + c0] = u;
            } else {
                *(float4*)&((float*)outv)[(size_t)row * M + colb + c0] = v;
            }
        }
    }
}

// --- fused FC head: h5 = relu(h4 @ Wf1 + bf1); out = tanh(h5 @ Wf2 + bf2) ---
// h4 bf16 128-wide in; h5 64x32 tile kept in LDS (aliased onto dead As).
__global__ __launch_bounds__(256) void head_kernel(
        const unsigned short* __restrict__ A, const float* __restrict__ Wf1,
        const float* __restrict__ bf1, const float* __restrict__ Wf2,
        const float* __restrict__ bf2, float* __restrict__ out, int N) {
    constexpr int K = 128, MB = 32, RT = 2, CG = 8, TM = 64, KP = K + 4;
    __shared__ float As[TM * KP];        // reused as h5 tile after k-loop
    __shared__ float Ws[K * MB];
    __shared__ float bs[MB];
    __shared__ float wt2[10 * 32];       // Wf2 transposed: wt2[m*32+k]
    __shared__ float bs2[10];
    const int t = threadIdx.x;
    const int base = blockIdx.x * TM;
    const int rows_valid = min(TM, N - base);
    constexpr int KD8 = K / 8;
    for (int idx = t; idx < TM * KD8; idx += 256) {
        int row = idx / KD8, kc = idx % KD8;
        if (row < rows_valid) {
            ushort8v u = *(const ushort8v*)&A[(size_t)(base + row) * K + kc * 8];
            float4 lo = {bf_to_f(u[0]), bf_to_f(u[1]), bf_to_f(u[2]), bf_to_f(u[3])};
            float4 hi = {bf_to_f(u[4]), bf_to_f(u[5]), bf_to_f(u[6]), bf_to_f(u[7])};
            *(float4*)&As[row * KP + kc * 8] = lo;
            *(float4*)&As[row * KP + kc * 8 + 4] = hi;
        }
    }
    for (int idx = t; idx < K * MB / 4; idx += 256) {
        int k = idx / (MB / 4), c4 = idx % (MB / 4);
        *(float4*)&Ws[k * MB + c4 * 4] = *(const float4*)&Wf1[(size_t)k * MB + c4 * 4];
    }
    if (t < MB) bs[t] = bf1[t];
    for (int idx = t; idx < 320; idx += 256)                 // R12 FIX: loop,
        wt2[(idx % 10) * 32 + idx / 10] = Wf2[idx];          // not `if (t<320)`
    if (t < 10) bs2[t] = bf2[t];
    __syncthreads();

    const int tc = t % CG;
    const int r0 = (t / CG) * RT;
    const int c0 = tc * 4;
    float4 acc[RT];
#pragma unroll
    for (int r = 0; r < RT; r++) acc[r] = {0.f, 0.f, 0.f, 0.f};
#pragma unroll 4
    for (int k = 0; k < K; k += 4) {
        float4 w0 = *(const float4*)&Ws[(k + 0) * MB + c0];
        float4 w1 = *(const float4*)&Ws[(k + 1) * MB + c0];
        float4 w2 = *(const float4*)&Ws[(k + 2) * MB + c0];
        float4 w3 = *(const float4*)&Ws[(k + 3) * MB + c0];
#pragma unroll
        for (int r = 0; r < RT; r++) {
            float4 av = *(const float4*)&As[(r0 + r) * KP + k];
            acc[r].x += av.x * w0.x + av.y * w1.x + av.z * w2.x + av.w * w3.x;
            acc[r].y += av.x * w0.y + av.y * w1.y + av.z * w2.y + av.w * w3.y;
            acc[r].z += av.x * w0.z + av.y * w1.z + av.z * w2.z + av.w * w3.z;
            acc[r].w += av.x * w0.w + av.y * w1.w + av.z * w2.w + av.w * w3.w;
        }
    }
    __syncthreads();                     // all As reads done -> safe to alias
    float* h5s = As;                     // 64 x 32 tile, stride 33
#pragma unroll
    for (int r = 0; r < RT; r++) {
        int row = r0 + r;
        float4 bv = *(const float4*)&bs[c0];
        h5s[row * 33 + c0 + 0] = fmaxf(acc[r].x + bv.x, 0.f);
        h5s[row * 33 + c0 + 1] = fmaxf(acc[r].y + bv.y, 0.f);
        h5s[row * 33 + c0 + 2] = fmaxf(acc[r].z + bv.z, 0.f);
        h5s[row * 33 + c0 + 3] = fmaxf(acc[r].w + bv.w, 0.f);
    }
    __syncthreads();
    const int lrow = t >> 2;             // 0..63
    const int q = t & 3;
    const int grow = base + lrow;
    if (grow < N) {
        for (int m = q; m < 10; m += 4) {
            float a = bs2[m];
#pragma unroll
            for (int k = 0; k < 32; k++) a += h5s[lrow * 33 + k] * wt2[m * 32 + k];
            out[(size_t)grow * 10 + m] = tanhf(a);
        }
    }
}

extern "C" void kernel_launch(void* const* d_in, const int* in_sizes, int n_in,
                              void* d_out, int out_size, void* d_ws, size_t ws_size,
                              hipStream_t stream) {
    const float* x   = (const float*)d_in[0];
    const int*   ei  = (const int*)d_in[1];     // int32 on device
    const float* W1  = (const float*)d_in[2];
    const float* b1  = (const float*)d_in[3];
    const float* W2  = (const float*)d_in[4];
    const float* b2  = (const float*)d_in[5];
    const float* W3  = (const float*)d_in[6];
    const float* b3  = (const float*)d_in[7];
    const float* W4  = (const float*)d_in[8];
    const float* b4  = (const float*)d_in[9];
    const float* Wf1 = (const float*)d_in[10];
    const float* bf1 = (const float*)d_in[11];
    const float* Wf2 = (const float*)d_in[12];
    const float* bf2 = (const float*)d_in[13];

    const int N = in_sizes[0] / 128;   // 100000
    const int E = in_sizes[1] / 2;     // 1600000
    const int* e_src = ei;
    const int* e_dst = ei + E;

    char* p = (char*)d_ws;
    auto carve = [&](size_t bytes) -> void* {
        void* r = (void*)p;
        p += (bytes + 255) & ~(size_t)255;
        return r;
    };
    int*   bucket_cnt = (int*)carve(512 * 4);
    int*   bucket_sta = (int*)carve(512 * 4);
    int*   bucket_cur = (int*)carve(512 * 4);
    float* dinv       = (float*)carve((size_t)N * 4);
    int*   row_ptr    = (int*)carve((size_t)(N + 1) * 4);
    int*   csr_tmp    = (int*)carve((size_t)E * 4);
    int*   csr_src    = (int*)carve((size_t)E * 4);
    unsigned short* bufP = (unsigned short*)carve((size_t)N * 128 * 2); // bf16 ping
    unsigned short* bufQ = (unsigned short*)carve((size_t)N * 128 * 2); // bf16 pong

    const int AGB = (N + 3) / 4;
    const int GB  = (N + 63) / 64;     // 1563 row-blocks

    // --- graph preprocessing: bucket hist, scan, place, bsort(+dinv) ---
    zero_kernel<<<2, 256, 0, stream>>>(bucket_cnt, 512);
    hist_kernel<<<PREB, 256, 0, stream>>>(e_dst, bucket_cnt, E);
    bucket_scan_kernel<<<1, 512, 0, stream>>>(bucket_cnt, bucket_sta, bucket_cur, E);
    place_kernel<<<PREB, 256, 0, stream>>>(e_src, e_dst, bucket_cur, csr_tmp, E);
    bsort_kernel<<<NBUCK, 256, 0, stream>>>(bucket_sta, csr_tmp, row_ptr, csr_src, dinv, N, E);

    // --- L1 (128->16): prescaled GEMM -> bf16 z1 (3.2MB, per-XCD L2-fit) ---
    gemm_kernel<128, 16, 16, 1, false, true, false, true><<<GB, 256, 0, stream>>>(
        x, W1, nullptr, dinv, bufP, N);
    agg_bf_kernel<16, 4, true, true><<<AGB, 256, 0, stream>>>(
        bufP, row_ptr, csr_src, dinv, b1, bufQ, N);

    // --- L2 (16->32): bf16 agg (L2-resident gather), GEMM -> bf16 z2 ---
    agg_bf_kernel<16, 4, false, false><<<AGB, 256, 0, stream>>>(
        bufQ, row_ptr, csr_src, dinv, nullptr, bufP, N);
    gemm_kernel<16, 32, 32, 2, true, true, true, true><<<GB, 256, 0, stream>>>(
        bufP, W2, b2, dinv, bufQ, N);

    // --- L3 (32->64): bf16 agg, GEMM -> bf16 z3 ---
    agg_bf_kernel<32, 8, false, false><<<AGB, 256, 0, stream>>>(
        bufQ, row_ptr, csr_src, dinv, nullptr, bufP, N);
    gemm_kernel<32, 64, 64, 4, true, true, true, true><<<GB, 256, 0, stream>>>(
        bufP, W3, b3, dinv, bufQ, N);

    // --- L4 (64->128): bf16 agg, M-split GEMM -> bf16 h4 ---
    agg_bf_kernel<64, 8, false, false><<<AGB, 256, 0, stream>>>(
        bufQ, row_ptr, csr_src, dinv, nullptr, bufP, N);
    gemm_kernel<64, 128, 64, 4, true, false, true, true><<<GB * 2, 256, 0, stream>>>(
        bufP, W4, b4, nullptr, bufQ, N);

    // --- fused FC head: relu(h4 Wf1 + bf1) -> tanh(. Wf2 + bf2) ---
    head_kernel<<<GB, 256, 0, stream>>>(bufQ, Wf1, bf1, Wf2, bf2, (float*)d_out, N);
}